// Round 3
// baseline (188.911 us; speedup 1.0000x reference)
//
#include <hip/hip_runtime.h>
#include <hip/hip_bf16.h>
#include <math.h>

#define IH 48
#define IW 48
#define NN 2304          // N = IH*IW
#define CC 256           // channels
#define NH 8
#define HD 32
#define HID 1024
#define NBIAS 9025       // (2*48-1)^2
#define SCALE 0.17677669529663687f
#define LOG2E 1.4426950408889634f
#define LN_EPS 1e-5f

typedef __attribute__((ext_vector_type(8))) short bf16x8;   // 8 bf16 in 4 VGPRs
typedef __attribute__((ext_vector_type(4))) short bf16x4;   // 4 bf16 in 2 VGPRs
typedef __attribute__((ext_vector_type(4))) float f32x4;

__device__ __forceinline__ short f2b(float f) {
    __hip_bfloat16 h = __float2bfloat16(f);
    short s; __builtin_memcpy(&s, &h, 2); return s;
}
__device__ __forceinline__ float b2f(short s) {
    __hip_bfloat16 h; __builtin_memcpy(&h, &s, 2); return __bfloat162float(h);
}
__device__ __forceinline__ float fast_exp2(float x) {
#if __has_builtin(__builtin_amdgcn_exp2f)
    return __builtin_amdgcn_exp2f(x);     // single v_exp_f32
#else
    return exp2f(x);
#endif
}

// ------- Prep: ln1 (blocks 0..NN-1) + weight/bias bf16 conversion ----------
// bias table is pre-multiplied by LOG2E so attention can use exp2 directly.
__global__ void prep_kernel(const float* __restrict__ x, const float* __restrict__ g,
                            const float* __restrict__ b, short* __restrict__ t1,
                            const float* __restrict__ w_qkv, const float* __restrict__ w_proj,
                            const float* __restrict__ w_fc1, const float* __restrict__ w_fc2,
                            const float* __restrict__ bt,
                            short* __restrict__ o_qkv, short* __restrict__ o_proj,
                            short* __restrict__ o_fc1, short* __restrict__ o_fc2,
                            short* __restrict__ o_bias)
{
    const int bid = blockIdx.x, tid = threadIdx.x;
    if (bid < NN) {        // ---- LayerNorm row ----
        __shared__ float red[8];
        float v = x[bid * CC + tid];
        float s = v, s2 = v * v;
        #pragma unroll
        for (int off = 32; off > 0; off >>= 1) {
            s  += __shfl_xor(s, off);
            s2 += __shfl_xor(s2, off);
        }
        const int wid = tid >> 6;
        if ((tid & 63) == 0) { red[wid * 2] = s; red[wid * 2 + 1] = s2; }
        __syncthreads();
        float tot  = red[0] + red[2] + red[4] + red[6];
        float tot2 = red[1] + red[3] + red[5] + red[7];
        float mu   = tot * (1.0f / CC);
        float var  = tot2 * (1.0f / CC) - mu * mu;
        float rstd = rsqrtf(var + LN_EPS);
        t1[bid * CC + tid] = f2b((v - mu) * rstd * g[tid] + b[tid]);
        return;
    }
    // ---- weight conversions, flat grid-stride over 858632 elements ----
    const int stride = (gridDim.x - NN) * 256;
    for (int i = (bid - NN) * 256 + tid; i < 858632; i += stride) {
        int j = i;
        if (j < 196608)            { int n = j >> 8,  k = j & 255;  o_qkv [j] = f2b(w_qkv [k * 768  + n]); }
        else if ((j -= 196608) < 65536)  { int n = j >> 8,  k = j & 255;  o_proj[j] = f2b(w_proj[k * 256  + n]); }
        else if ((j -= 65536)  < 262144) { int n = j >> 8,  k = j & 255;  o_fc1 [j] = f2b(w_fc1 [k * 1024 + n]); }
        else if ((j -= 262144) < 262144) { int n = j >> 10, k = j & 1023; o_fc2 [j] = f2b(w_fc2 [k * 256  + n]); }
        else { j -= 262144; int h = j / NBIAS, idx = j - h * NBIAS; o_bias[j] = f2b(bt[idx * NH + h] * LOG2E); }
    }
}

// ---------------- LayerNorm (standalone, for ln2) --------------------------
__global__ void ln_kernel(const float* __restrict__ x,
                          const float* __restrict__ g,
                          const float* __restrict__ b,
                          short* __restrict__ out)
{
    __shared__ float red[8];
    const int row = blockIdx.x, tid = threadIdx.x;
    float v = x[row * CC + tid];
    float s = v, s2 = v * v;
    #pragma unroll
    for (int off = 32; off > 0; off >>= 1) {
        s  += __shfl_xor(s, off);
        s2 += __shfl_xor(s2, off);
    }
    const int wid = tid >> 6;
    if ((tid & 63) == 0) { red[wid * 2] = s; red[wid * 2 + 1] = s2; }
    __syncthreads();
    float tot  = red[0] + red[2] + red[4] + red[6];
    float tot2 = red[1] + red[3] + red[5] + red[7];
    float mu   = tot * (1.0f / CC);
    float var  = tot2 * (1.0f / CC) - mu * mu;
    float rstd = rsqrtf(var + LN_EPS);
    out[row * CC + tid] = f2b((v - mu) * rstd * g[tid] + b[tid]);
}

// --- MFMA GEMM core: 64x64 tile, 4 waves, K-step 64, register-pipelined ----
#define GSTRIDE 72
template<int K>
__device__ __forceinline__ void mfma_gemm_core(const short* __restrict__ A,
                                               const short* __restrict__ BT,
                                               int m0, int n0, f32x4 acc[4],
                                               short* lds)
{
    short* As = lds;                 // [64][72]
    short* Bs = lds + 64 * GSTRIDE;  // [64][72]
    const int tid  = threadIdx.x;
    const int w    = tid >> 6, lane = tid & 63;
    const int quad = lane >> 4, l15 = lane & 15;
    const int sr = tid >> 2;            // staging row 0..63
    const int sc = (tid & 3) * 16;      // k-granule 0,16,32,48
    #pragma unroll
    for (int c = 0; c < 4; ++c) acc[c] = (f32x4){0.f, 0.f, 0.f, 0.f};

    const short* Ap = &A [(m0 + sr) * K + sc];
    const short* Bp = &BT[(n0 + sr) * K + sc];
    bf16x8 ra0 = *(const bf16x8*)Ap,       ra1 = *(const bf16x8*)(Ap + 8);
    bf16x8 rb0 = *(const bf16x8*)Bp,       rb1 = *(const bf16x8*)(Bp + 8);

    for (int k0 = 0; k0 < K; k0 += 64) {
        __syncthreads();                       // LDS consumers of tile k-1 done
        *(bf16x8*)&As[sr * GSTRIDE + sc]     = ra0;
        *(bf16x8*)&As[sr * GSTRIDE + sc + 8] = ra1;
        *(bf16x8*)&Bs[sr * GSTRIDE + sc]     = rb0;
        *(bf16x8*)&Bs[sr * GSTRIDE + sc + 8] = rb1;
        if (k0 + 64 < K) {                     // prefetch tile k+1 (overlaps below)
            ra0 = *(const bf16x8*)(Ap + k0 + 64);
            ra1 = *(const bf16x8*)(Ap + k0 + 72);
            rb0 = *(const bf16x8*)(Bp + k0 + 64);
            rb1 = *(const bf16x8*)(Bp + k0 + 72);
        }
        __syncthreads();                       // tile k visible
        #pragma unroll
        for (int s = 0; s < 2; ++s) {
            bf16x8 a = *(const bf16x8*)&As[(w * 16 + l15) * GSTRIDE + s * 32 + quad * 8];
            #pragma unroll
            for (int c = 0; c < 4; ++c) {
                bf16x8 b = *(const bf16x8*)&Bs[(c * 16 + l15) * GSTRIDE + s * 32 + quad * 8];
                acc[c] = __builtin_amdgcn_mfma_f32_16x16x32_bf16(a, b, acc[c], 0, 0, 0);
            }
        }
    }
}
// C/D layout [m89]: col = n-tile*16 + (lane&15), row = 16w + quad*4 + reg.

// ---------------- QKV: t1 @ w_qkvT -> qb, kb (bf16 [h][n][d]), vT [h][d][n]-
// q is pre-scaled by SCALE*LOG2E so attention softmax can use exp2 directly.
__global__ void qkv_kernel(const short* __restrict__ t1, const short* __restrict__ wT,
                           short* __restrict__ qb, short* __restrict__ kb,
                           short* __restrict__ vT)
{
    __shared__ short lds[2 * 64 * GSTRIDE];
    f32x4 acc[4];
    const int m0 = blockIdx.y * 64, n0 = blockIdx.x * 64;
    mfma_gemm_core<256>(t1, wT, m0, n0, acc, lds);
    const int lane = threadIdx.x & 63, w = threadIdx.x >> 6;
    const int quad = lane >> 4, l15 = lane & 15;
    #pragma unroll
    for (int c = 0; c < 4; ++c) {
        int col = n0 + c * 16 + l15;
        int three = col >> 8, rem = col & 255;
        int h = rem >> 5, d = rem & 31;
        #pragma unroll
        for (int r = 0; r < 4; ++r) {
            int row = m0 + w * 16 + quad * 4 + r;
            float v = acc[c][r];
            if (three == 0)      qb[(h * NN + row) * HD + d] = f2b(v * (SCALE * LOG2E));
            else if (three == 1) kb[(h * NN + row) * HD + d] = f2b(v);
            else                 vT[(h * HD + d) * NN + row] = f2b(v);
        }
    }
}

// -------- MFMA flash attention: swapped-QK, register-resident P ------------
// mfma(K,Q) -> lane holds P^T[key=quad*4+r][q=l15]. PV contraction slots are
// permuted so each lane's 8 P values ARE its PV A-fragment (no LDS, no
// cross-lane moves). V B-fragment loads with the same permutation.
// Round-2 lesson: with ~4.5 blocks/CU there is no TLP to hide the 14 global
// loads/iter; depth-1 REGISTER PREFETCH (same pattern as mfma_gemm_core)
// issues iteration c+1's K/V/bias loads before computing iteration c.
#define DECL_BUF(S) \
    bf16x8 k0##S, k1##S; bf16x4 va0##S, vb0##S, va1##S, vb1##S; \
    short ba0##S, ba1##S, ba2##S, ba3##S, bb0##S, bb1##S, bb2##S, bb3##S;

#define LOAD_ITER(T, S) { \
    const int t_ = (T); \
    k0##S = *(const bf16x8*)&kb[(h * NN + t_      + l15) * HD + quad * 8]; \
    k1##S = *(const bf16x8*)&kb[(h * NN + t_ + 16 + l15) * HD + quad * 8]; \
    const short* vp0_ = &vT[(h * HD + l15)      * NN + t_ + quad * 4]; \
    const short* vp1_ = &vT[(h * HD + 16 + l15) * NN + t_ + quad * 4]; \
    va0##S = *(const bf16x4*)vp0_;  vb0##S = *(const bf16x4*)(vp0_ + 16); \
    va1##S = *(const bf16x4*)vp1_;  vb1##S = *(const bf16x4*)(vp1_ + 16); \
    const int kA_ = t_ + quad * 4, kB_ = kA_ + 16; \
    const short* pA_ = bt + (qbase - ((kA_ / IW) * 95 + kA_ % IW)); \
    const short* pB_ = bt + (qbase - ((kB_ / IW) * 95 + kB_ % IW)); \
    ba0##S = pA_[0]; ba1##S = pA_[-1]; ba2##S = pA_[-2]; ba3##S = pA_[-3]; \
    bb0##S = pB_[0]; bb1##S = pB_[-1]; bb2##S = pB_[-2]; bb3##S = pB_[-3]; \
}

#define COPY_BUF(D, S) \
    k0##D = k0##S; k1##D = k1##S; \
    va0##D = va0##S; vb0##D = vb0##S; va1##D = va1##S; vb1##D = vb1##S; \
    ba0##D = ba0##S; ba1##D = ba1##S; ba2##D = ba2##S; ba3##D = ba3##S; \
    bb0##D = bb0##S; bb1##D = bb1##S; bb2##D = bb2##S; bb3##D = bb3##S;

#define COMPUTE_ITER(S) { \
    f32x4 s0_ = __builtin_amdgcn_mfma_f32_16x16x32_bf16(k0##S, qf, zero, 0, 0, 0); \
    f32x4 s1_ = __builtin_amdgcn_mfma_f32_16x16x32_bf16(k1##S, qf, zero, 0, 0, 0); \
    float p0_ = fast_exp2(s0_[0] + b2f(ba0##S)); \
    float p1_ = fast_exp2(s0_[1] + b2f(ba1##S)); \
    float p2_ = fast_exp2(s0_[2] + b2f(ba2##S)); \
    float p3_ = fast_exp2(s0_[3] + b2f(ba3##S)); \
    float p4_ = fast_exp2(s1_[0] + b2f(bb0##S)); \
    float p5_ = fast_exp2(s1_[1] + b2f(bb1##S)); \
    float p6_ = fast_exp2(s1_[2] + b2f(bb2##S)); \
    float p7_ = fast_exp2(s1_[3] + b2f(bb3##S)); \
    lp += (p0_ + p1_) + (p2_ + p3_) + (p4_ + p5_) + (p6_ + p7_); \
    bf16x8 pa_ = (bf16x8){ f2b(p0_), f2b(p1_), f2b(p2_), f2b(p3_), \
                           f2b(p4_), f2b(p5_), f2b(p6_), f2b(p7_) }; \
    bf16x8 v0_ = (bf16x8){ va0##S[0], va0##S[1], va0##S[2], va0##S[3], \
                           vb0##S[0], vb0##S[1], vb0##S[2], vb0##S[3] }; \
    bf16x8 v1_ = (bf16x8){ va1##S[0], va1##S[1], va1##S[2], va1##S[3], \
                           vb1##S[0], vb1##S[1], vb1##S[2], vb1##S[3] }; \
    O0 = __builtin_amdgcn_mfma_f32_16x16x32_bf16(pa_, v0_, O0, 0, 0, 0); \
    O1 = __builtin_amdgcn_mfma_f32_16x16x32_bf16(pa_, v1_, O1, 0, 0, 0); \
}

__global__ __launch_bounds__(256) void attn_kernel(
        const short* __restrict__ qb, const short* __restrict__ kb,
        const short* __restrict__ vT, const short* __restrict__ biasT,
        short* __restrict__ o)
{
    __shared__ float Ored[4][16][33];
    __shared__ float lred[4][16];
    const int w = threadIdx.x >> 6, lane = threadIdx.x & 63;
    const int quad = lane >> 4, l15 = lane & 15;
    const int h = blockIdx.x / 144, q0 = (blockIdx.x % 144) * 16;
    const int t0 = w * 576;
    const short* bt = &biasT[h * NBIAS];

    // Q fragment: B[n=q=l15][k=quad*8+j]  (q pre-scaled by SCALE*LOG2E)
    bf16x8 qf = *(const bf16x8*)&qb[(h * NN + q0 + l15) * HD + quad * 8];

    // per-lane q coords: 16-row q-tiles never straddle image rows (16 | 48)
    const int qi = q0 / IW, qj = (q0 % IW) + l15;
    const int qbase = (qi + 47) * 95 + (qj + 47);

    f32x4 O0 = (f32x4){0.f,0.f,0.f,0.f}, O1 = (f32x4){0.f,0.f,0.f,0.f};
    float lp = 0.f;
    const f32x4 zero = (f32x4){0.f,0.f,0.f,0.f};

    DECL_BUF(c)
    DECL_BUF(n)
    LOAD_ITER(t0, c)
    for (int it = 0; it < 17; ++it) {
        LOAD_ITER(t0 + (it + 1) * 32, n)   // prefetch next chunk (overlaps below)
        COMPUTE_ITER(c)
        COPY_BUF(c, n)                     // waitcnt lands here, a body late
    }
    COMPUTE_ITER(c)

    // lp is per-lane (q=l15): reduce across the 4 quad-lanes sharing l15
    lp += __shfl_xor(lp, 16);
    lp += __shfl_xor(lp, 32);
    if (quad == 0) lred[w][l15] = lp;
    // O: row = q = quad*4+r, col = dim = l15 (O0) / 16+l15 (O1)
    #pragma unroll
    for (int r = 0; r < 4; ++r) {
        Ored[w][quad * 4 + r][l15]      = O0[r];
        Ored[w][quad * 4 + r][16 + l15] = O1[r];
    }
    __syncthreads();
    {   // 256 threads combine 16 q-rows x 32 dims (2 rows per thread)
        const int col = threadIdx.x & 31;
        for (int rr = threadIdx.x >> 5; rr < 16; rr += 8) {
            float s = 0.f, l = 0.f;
            #pragma unroll
            for (int pw = 0; pw < 4; ++pw) { s += Ored[pw][rr][col]; l += lred[pw][rr]; }
            o[(q0 + rr) * CC + h * HD + col] = f2b(s / l);
        }
    }
}

// ---------------- proj: o @ w_projT + b_proj + x -> x2 (fp32) --------------
__global__ void proj_kernel(const short* __restrict__ o, const short* __restrict__ wT,
                            const float* __restrict__ bias, const float* __restrict__ x_in,
                            float* __restrict__ x2)
{
    __shared__ short lds[2 * 64 * GSTRIDE];
    f32x4 acc[4];
    const int m0 = blockIdx.y * 64, n0 = blockIdx.x * 64;
    mfma_gemm_core<256>(o, wT, m0, n0, acc, lds);
    const int lane = threadIdx.x & 63, w = threadIdx.x >> 6;
    const int quad = lane >> 4, l15 = lane & 15;
    #pragma unroll
    for (int c = 0; c < 4; ++c) {
        int col = n0 + c * 16 + l15;
        #pragma unroll
        for (int r = 0; r < 4; ++r) {
            int row = m0 + w * 16 + quad * 4 + r;
            x2[row * CC + col] = acc[c][r] + bias[col] + x_in[row * CC + col];
        }
    }
}

// ---------------- fc1: t2 @ w_fc1T + b_fc1, GELU -> h1 (bf16) --------------
__global__ void fc1_kernel(const short* __restrict__ t2, const short* __restrict__ wT,
                           const float* __restrict__ bias, short* __restrict__ h1)
{
    __shared__ short lds[2 * 64 * GSTRIDE];
    f32x4 acc[4];
    const int m0 = blockIdx.y * 64, n0 = blockIdx.x * 64;
    mfma_gemm_core<256>(t2, wT, m0, n0, acc, lds);
    const int lane = threadIdx.x & 63, w = threadIdx.x >> 6;
    const int quad = lane >> 4, l15 = lane & 15;
    #pragma unroll
    for (int c = 0; c < 4; ++c) {
        int col = n0 + c * 16 + l15;
        #pragma unroll
        for (int r = 0; r < 4; ++r) {
            int row = m0 + w * 16 + quad * 4 + r;
            float v = acc[c][r] + bias[col];
            float ge = 0.5f * v * (1.0f + erff(v * 0.7071067811865476f));
            h1[row * HID + col] = f2b(ge);
        }
    }
}

// ---------------- fc2: h1 @ w_fc2T + b_fc2 + x2 -> out (fp32) --------------
__global__ void fc2_kernel(const short* __restrict__ h1, const short* __restrict__ wT,
                           const float* __restrict__ bias, const float* __restrict__ x2,
                           float* __restrict__ out)
{
    __shared__ short lds[2 * 64 * GSTRIDE];
    f32x4 acc[4];
    const int m0 = blockIdx.y * 64, n0 = blockIdx.x * 64;
    mfma_gemm_core<1024>(h1, wT, m0, n0, acc, lds);
    const int lane = threadIdx.x & 63, w = threadIdx.x >> 6;
    const int quad = lane >> 4, l15 = lane & 15;
    #pragma unroll
    for (int c = 0; c < 4; ++c) {
        int col = n0 + c * 16 + l15;
        #pragma unroll
        for (int r = 0; r < 4; ++r) {
            int row = m0 + w * 16 + quad * 4 + r;
            out[row * CC + col] = acc[c][r] + bias[col] + x2[row * CC + col];
        }
    }
}

extern "C" void kernel_launch(void* const* d_in, const int* in_sizes, int n_in,
                              void* d_out, int out_size, void* d_ws, size_t ws_size,
                              hipStream_t stream)
{
    const float* x          = (const float*)d_in[0];
    const float* gamma1     = (const float*)d_in[1];
    const float* beta1      = (const float*)d_in[2];
    const float* w_qkv      = (const float*)d_in[3];
    const float* w_proj     = (const float*)d_in[4];
    const float* b_proj     = (const float*)d_in[5];
    const float* bias_table = (const float*)d_in[6];
    const float* gamma2     = (const float*)d_in[7];
    const float* beta2      = (const float*)d_in[8];
    const float* w_fc1      = (const float*)d_in[9];
    const float* b_fc1      = (const float*)d_in[10];
    const float* w_fc2      = (const float*)d_in[11];
    const float* b_fc2      = (const float*)d_in[12];
    // d_in[13] = rel_idx (int32) — unused: bias index computed analytically.

    short* S = (short*)d_ws;
    const int NC = NN * CC;               // 589824
    short* t1     = S;                    // bf16 [N][C]
    short* qb     = t1  + NC;             // bf16 [h][n][d]
    short* kb     = qb  + NC;             // bf16 [h][n][d]
    short* vT     = kb  + NC;             // bf16 [h][d][n]
    short* obuf   = vT  + NC;             // bf16 [N][C]
    short* t2     = obuf+ NC;             // bf16 [N][C]
    short* h1     = t2  + NC;             // bf16 [N][HID]
    short* wTqkv  = h1  + NN * HID;       // bf16 [768][256]
    short* wTproj = wTqkv  + 768 * 256;   // bf16 [256][256]
    short* wTfc1  = wTproj + 256 * 256;   // bf16 [1024][256]
    short* wTfc2  = wTfc1  + 1024 * 256;  // bf16 [256][1024]
    short* biasT  = wTfc2  + 256 * 1024;  // bf16 [NH][9025] (pre-scaled by LOG2E)
    float* x2     = (float*)(biasT + NH * NBIAS + 8);  // fp32 [N][C]

    prep_kernel<<<NN + 512, 256, 0, stream>>>(x, gamma1, beta1, t1,
                                              w_qkv, w_proj, w_fc1, w_fc2, bias_table,
                                              wTqkv, wTproj, wTfc1, wTfc2, biasT);
    qkv_kernel<<<dim3(12, 36), 256, 0, stream>>>(t1, wTqkv, qb, kb, vT);
    attn_kernel<<<1152, 256, 0, stream>>>(qb, kb, vT, biasT, obuf);
    proj_kernel<<<dim3(4, 36), 256, 0, stream>>>(obuf, wTproj, b_proj, x, x2);
    ln_kernel<<<NN, 256, 0, stream>>>(x2, gamma2, beta2, t2);
    fc1_kernel<<<dim3(16, 36), 256, 0, stream>>>(t2, wTfc1, b_fc1, h1);
    fc2_kernel<<<dim3(4, 36), 256, 0, stream>>>(h1, wTfc2, b_fc2, x2,
                                                (float*)d_out);
}

// Round 4
// 186.094 us; speedup vs baseline: 1.0151x; 1.0151x over previous
//
#include <hip/hip_runtime.h>
#include <hip/hip_bf16.h>
#include <math.h>

#define IH 48
#define IW 48
#define NN 2304          // N = IH*IW
#define CC 256           // channels
#define NH 8
#define HD 32
#define HID 1024
#define NBIAS 9025       // (2*48-1)^2
#define SCALE 0.17677669529663687f
#define LOG2E 1.4426950408889634f
#define LN_EPS 1e-5f
#define NSPLIT 3         // attention key-split factor (TLP: 3456 blocks)

typedef __attribute__((ext_vector_type(8))) short bf16x8;   // 8 bf16 in 4 VGPRs
typedef __attribute__((ext_vector_type(4))) short bf16x4;   // 4 bf16 in 2 VGPRs
typedef __attribute__((ext_vector_type(4))) float f32x4;

__device__ __forceinline__ short f2b(float f) {
    __hip_bfloat16 h = __float2bfloat16(f);
    short s; __builtin_memcpy(&s, &h, 2); return s;
}
__device__ __forceinline__ float b2f(short s) {
    __hip_bfloat16 h; __builtin_memcpy(&h, &s, 2); return __bfloat162float(h);
}
__device__ __forceinline__ float fast_exp2(float x) {
#if __has_builtin(__builtin_amdgcn_exp2f)
    return __builtin_amdgcn_exp2f(x);     // single v_exp_f32
#else
    return exp2f(x);
#endif
}

// ------- Prep: ln1 (blocks 0..NN-1) + weight/bias conversion ---------------
// bias table -> f32, pre-multiplied by LOG2E (attn adds it pre-exp2, no cvt).
__global__ void prep_kernel(const float* __restrict__ x, const float* __restrict__ g,
                            const float* __restrict__ b, short* __restrict__ t1,
                            const float* __restrict__ w_qkv, const float* __restrict__ w_proj,
                            const float* __restrict__ w_fc1, const float* __restrict__ w_fc2,
                            const float* __restrict__ bt,
                            short* __restrict__ o_qkv, short* __restrict__ o_proj,
                            short* __restrict__ o_fc1, short* __restrict__ o_fc2,
                            float* __restrict__ o_bias)
{
    const int bid = blockIdx.x, tid = threadIdx.x;
    if (bid < NN) {        // ---- LayerNorm row ----
        __shared__ float red[8];
        float v = x[bid * CC + tid];
        float s = v, s2 = v * v;
        #pragma unroll
        for (int off = 32; off > 0; off >>= 1) {
            s  += __shfl_xor(s, off);
            s2 += __shfl_xor(s2, off);
        }
        const int wid = tid >> 6;
        if ((tid & 63) == 0) { red[wid * 2] = s; red[wid * 2 + 1] = s2; }
        __syncthreads();
        float tot  = red[0] + red[2] + red[4] + red[6];
        float tot2 = red[1] + red[3] + red[5] + red[7];
        float mu   = tot * (1.0f / CC);
        float var  = tot2 * (1.0f / CC) - mu * mu;
        float rstd = rsqrtf(var + LN_EPS);
        t1[bid * CC + tid] = f2b((v - mu) * rstd * g[tid] + b[tid]);
        return;
    }
    // ---- weight conversions, flat grid-stride over 858632 elements ----
    const int stride = (gridDim.x - NN) * 256;
    for (int i = (bid - NN) * 256 + tid; i < 858632; i += stride) {
        int j = i;
        if (j < 196608)            { int n = j >> 8,  k = j & 255;  o_qkv [j] = f2b(w_qkv [k * 768  + n]); }
        else if ((j -= 196608) < 65536)  { int n = j >> 8,  k = j & 255;  o_proj[j] = f2b(w_proj[k * 256  + n]); }
        else if ((j -= 65536)  < 262144) { int n = j >> 8,  k = j & 255;  o_fc1 [j] = f2b(w_fc1 [k * 1024 + n]); }
        else if ((j -= 262144) < 262144) { int n = j >> 10, k = j & 1023; o_fc2 [j] = f2b(w_fc2 [k * 256  + n]); }
        else { j -= 262144; int h = j / NBIAS, idx = j - h * NBIAS; o_bias[j] = bt[idx * NH + h] * LOG2E; }
    }
}

// ---------------- LayerNorm (standalone, for ln2) --------------------------
__global__ void ln_kernel(const float* __restrict__ x,
                          const float* __restrict__ g,
                          const float* __restrict__ b,
                          short* __restrict__ out)
{
    __shared__ float red[8];
    const int row = blockIdx.x, tid = threadIdx.x;
    float v = x[row * CC + tid];
    float s = v, s2 = v * v;
    #pragma unroll
    for (int off = 32; off > 0; off >>= 1) {
        s  += __shfl_xor(s, off);
        s2 += __shfl_xor(s2, off);
    }
    const int wid = tid >> 6;
    if ((tid & 63) == 0) { red[wid * 2] = s; red[wid * 2 + 1] = s2; }
    __syncthreads();
    float tot  = red[0] + red[2] + red[4] + red[6];
    float tot2 = red[1] + red[3] + red[5] + red[7];
    float mu   = tot * (1.0f / CC);
    float var  = tot2 * (1.0f / CC) - mu * mu;
    float rstd = rsqrtf(var + LN_EPS);
    out[row * CC + tid] = f2b((v - mu) * rstd * g[tid] + b[tid]);
}

// --- MFMA GEMM core: 64x64 tile, 4 waves, K-step 64, register-pipelined ----
#define GSTRIDE 72
template<int K>
__device__ __forceinline__ void mfma_gemm_core(const short* __restrict__ A,
                                               const short* __restrict__ BT,
                                               int m0, int n0, f32x4 acc[4],
                                               short* lds)
{
    short* As = lds;                 // [64][72]
    short* Bs = lds + 64 * GSTRIDE;  // [64][72]
    const int tid  = threadIdx.x;
    const int w    = tid >> 6, lane = tid & 63;
    const int quad = lane >> 4, l15 = lane & 15;
    const int sr = tid >> 2;            // staging row 0..63
    const int sc = (tid & 3) * 16;      // k-granule 0,16,32,48
    #pragma unroll
    for (int c = 0; c < 4; ++c) acc[c] = (f32x4){0.f, 0.f, 0.f, 0.f};

    const short* Ap = &A [(m0 + sr) * K + sc];
    const short* Bp = &BT[(n0 + sr) * K + sc];
    bf16x8 ra0 = *(const bf16x8*)Ap,       ra1 = *(const bf16x8*)(Ap + 8);
    bf16x8 rb0 = *(const bf16x8*)Bp,       rb1 = *(const bf16x8*)(Bp + 8);

    for (int k0 = 0; k0 < K; k0 += 64) {
        __syncthreads();                       // LDS consumers of tile k-1 done
        *(bf16x8*)&As[sr * GSTRIDE + sc]     = ra0;
        *(bf16x8*)&As[sr * GSTRIDE + sc + 8] = ra1;
        *(bf16x8*)&Bs[sr * GSTRIDE + sc]     = rb0;
        *(bf16x8*)&Bs[sr * GSTRIDE + sc + 8] = rb1;
        if (k0 + 64 < K) {                     // prefetch tile k+1 (overlaps below)
            ra0 = *(const bf16x8*)(Ap + k0 + 64);
            ra1 = *(const bf16x8*)(Ap + k0 + 72);
            rb0 = *(const bf16x8*)(Bp + k0 + 64);
            rb1 = *(const bf16x8*)(Bp + k0 + 72);
        }
        __syncthreads();                       // tile k visible
        #pragma unroll
        for (int s = 0; s < 2; ++s) {
            bf16x8 a = *(const bf16x8*)&As[(w * 16 + l15) * GSTRIDE + s * 32 + quad * 8];
            #pragma unroll
            for (int c = 0; c < 4; ++c) {
                bf16x8 b = *(const bf16x8*)&Bs[(c * 16 + l15) * GSTRIDE + s * 32 + quad * 8];
                acc[c] = __builtin_amdgcn_mfma_f32_16x16x32_bf16(a, b, acc[c], 0, 0, 0);
            }
        }
    }
}
// C/D layout [m89]: col = n-tile*16 + (lane&15), row = 16w + quad*4 + reg.

// ---------------- QKV: t1 @ w_qkvT -> qb, kb (bf16 [h][n][d]), vT [h][d][n]-
// q is pre-scaled by SCALE*LOG2E so attention softmax can use exp2 directly.
__global__ void qkv_kernel(const short* __restrict__ t1, const short* __restrict__ wT,
                           short* __restrict__ qb, short* __restrict__ kb,
                           short* __restrict__ vT)
{
    __shared__ short lds[2 * 64 * GSTRIDE];
    f32x4 acc[4];
    const int m0 = blockIdx.y * 64, n0 = blockIdx.x * 64;
    mfma_gemm_core<256>(t1, wT, m0, n0, acc, lds);
    const int lane = threadIdx.x & 63, w = threadIdx.x >> 6;
    const int quad = lane >> 4, l15 = lane & 15;
    #pragma unroll
    for (int c = 0; c < 4; ++c) {
        int col = n0 + c * 16 + l15;
        int three = col >> 8, rem = col & 255;
        int h = rem >> 5, d = rem & 31;
        #pragma unroll
        for (int r = 0; r < 4; ++r) {
            int row = m0 + w * 16 + quad * 4 + r;
            float v = acc[c][r];
            if (three == 0)      qb[(h * NN + row) * HD + d] = f2b(v * (SCALE * LOG2E));
            else if (three == 1) kb[(h * NN + row) * HD + d] = f2b(v);
            else                 vT[(h * HD + d) * NN + row] = f2b(v);
        }
    }
}

// -------- MFMA flash attention: swapped-QK, register-resident P ------------
// mfma(K,Q) -> lane holds P^T[key=quad*4+r][q=l15]. PV contraction slots are
// permuted so each lane's 8 P values ARE its PV A-fragment (no LDS, no
// cross-lane moves). V B-fragment loads with the same permutation.
// Round-3 lesson: depth-1 reg prefetch was a NULL -> bottleneck is TLP, not
// per-body latency. Fix: key-split x3 (grid 3456, ~13.5 blocks/CU vs cap 8)
// writing fp32 partial (O,l); attn_norm_kernel combines.
__global__ __launch_bounds__(256) void attn_kernel(
        const short* __restrict__ qb, const short* __restrict__ kb,
        const short* __restrict__ vT, const float* __restrict__ biasF,
        float* __restrict__ Opart, float* __restrict__ lpart)
{
    __shared__ float Ored[4][16][33];
    __shared__ float lred[4][16];
    const int w = threadIdx.x >> 6, lane = threadIdx.x & 63;
    const int quad = lane >> 4, l15 = lane & 15;
    const int sp = blockIdx.x / 1152;             // key-split index 0..2
    const int bb = blockIdx.x - sp * 1152;
    const int h = bb / 144, q0 = (bb % 144) * 16;
    const int t0 = sp * (NN / NSPLIT) + w * (NN / NSPLIT / 4);   // 768*sp + 192*w
    const float* bt = &biasF[h * NBIAS];

    // Q fragment: B[n=q=l15][k=quad*8+j]  (q pre-scaled by SCALE*LOG2E)
    bf16x8 qf = *(const bf16x8*)&qb[(h * NN + q0 + l15) * HD + quad * 8];

    // per-lane q coords: 16-row q-tiles never straddle image rows (16 | 48)
    const int qi = q0 / IW, qj = (q0 % IW) + l15;
    const int qbase = (qi + 47) * 95 + (qj + 47);

    f32x4 O0 = (f32x4){0.f,0.f,0.f,0.f}, O1 = (f32x4){0.f,0.f,0.f,0.f};
    float lp = 0.f;
    const f32x4 zero = (f32x4){0.f,0.f,0.f,0.f};

    for (int c = 0; c < 6; ++c) {
        const int t = t0 + c * 32;
        bf16x8 k0f = *(const bf16x8*)&kb[(h * NN + t      + l15) * HD + quad * 8];
        bf16x8 k1f = *(const bf16x8*)&kb[(h * NN + t + 16 + l15) * HD + quad * 8];
        // V with permuted key slots: dim=l15 (O0) / 16+l15 (O1)
        const short* vp0 = &vT[(h * HD + l15)      * NN + t + quad * 4];
        const short* vp1 = &vT[(h * HD + 16 + l15) * NN + t + quad * 4];
        bf16x4 va0 = *(const bf16x4*)vp0, vb0 = *(const bf16x4*)(vp0 + 16);
        bf16x4 va1 = *(const bf16x4*)vp1, vb1 = *(const bf16x4*)(vp1 + 16);

        f32x4 s0 = __builtin_amdgcn_mfma_f32_16x16x32_bf16(k0f, qf, zero, 0, 0, 0);
        f32x4 s1 = __builtin_amdgcn_mfma_f32_16x16x32_bf16(k1f, qf, zero, 0, 0, 0);

        // bias base pointers for the two 4-key groups this lane owns
        // (4-aligned key groups never straddle image rows: 4 | 48)
        const int kA = t + quad * 4;
        const int kB = kA + 16;
        const float* pA = bt + (qbase - ((kA / IW) * 95 + kA % IW));
        const float* pB = bt + (qbase - ((kB / IW) * 95 + kB % IW));

        float p[8];
        #pragma unroll
        for (int r = 0; r < 4; ++r) {
            p[r]     = fast_exp2(s0[r] + pA[-r]);
            p[4 + r] = fast_exp2(s1[r] + pB[-r]);
        }
        #pragma unroll
        for (int r = 0; r < 8; ++r) lp += p[r];
        bf16x8 pa = (bf16x8){ f2b(p[0]), f2b(p[1]), f2b(p[2]), f2b(p[3]),
                              f2b(p[4]), f2b(p[5]), f2b(p[6]), f2b(p[7]) };
        bf16x8 v0 = (bf16x8){ va0[0], va0[1], va0[2], va0[3],
                              vb0[0], vb0[1], vb0[2], vb0[3] };
        bf16x8 v1 = (bf16x8){ va1[0], va1[1], va1[2], va1[3],
                              vb1[0], vb1[1], vb1[2], vb1[3] };
        O0 = __builtin_amdgcn_mfma_f32_16x16x32_bf16(pa, v0, O0, 0, 0, 0);
        O1 = __builtin_amdgcn_mfma_f32_16x16x32_bf16(pa, v1, O1, 0, 0, 0);
    }

    // lp is per-lane (q=l15): reduce across the 4 quad-lanes sharing l15
    lp += __shfl_xor(lp, 16);
    lp += __shfl_xor(lp, 32);
    if (quad == 0) lred[w][l15] = lp;
    // O: row = q = quad*4+r, col = dim = l15 (O0) / 16+l15 (O1)
    #pragma unroll
    for (int r = 0; r < 4; ++r) {
        Ored[w][quad * 4 + r][l15]      = O0[r];
        Ored[w][quad * 4 + r][16 + l15] = O1[r];
    }
    __syncthreads();
    {   // 256 threads combine 16 q-rows x 32 dims -> fp32 partials
        const int col = threadIdx.x & 31;
        for (int rr = threadIdx.x >> 5; rr < 16; rr += 8) {
            float s = 0.f, l = 0.f;
            #pragma unroll
            for (int pw = 0; pw < 4; ++pw) { s += Ored[pw][rr][col]; l += lred[pw][rr]; }
            Opart[sp * (NN * CC) + (q0 + rr) * CC + h * HD + col] = s;
            if (col == 0) lpart[(sp * NH + h) * NN + q0 + rr] = l;
        }
    }
}

// ------- combine key-split partials: obuf = (sum O) / (sum l), bf16 --------
__global__ void attn_norm_kernel(const float* __restrict__ Opart,
                                 const float* __restrict__ lpart,
                                 short* __restrict__ obuf)
{
    const int n = blockIdx.x, c = threadIdx.x, h = c >> 5;
    float v = Opart[n * CC + c] + Opart[NN * CC + n * CC + c]
            + Opart[2 * NN * CC + n * CC + c];
    float l = lpart[h * NN + n] + lpart[(NH + h) * NN + n]
            + lpart[(2 * NH + h) * NN + n];
    obuf[n * CC + c] = f2b(v / l);
}

// ---------------- proj: o @ w_projT + b_proj + x -> x2 (fp32) --------------
__global__ void proj_kernel(const short* __restrict__ o, const short* __restrict__ wT,
                            const float* __restrict__ bias, const float* __restrict__ x_in,
                            float* __restrict__ x2)
{
    __shared__ short lds[2 * 64 * GSTRIDE];
    f32x4 acc[4];
    const int m0 = blockIdx.y * 64, n0 = blockIdx.x * 64;
    mfma_gemm_core<256>(o, wT, m0, n0, acc, lds);
    const int lane = threadIdx.x & 63, w = threadIdx.x >> 6;
    const int quad = lane >> 4, l15 = lane & 15;
    #pragma unroll
    for (int c = 0; c < 4; ++c) {
        int col = n0 + c * 16 + l15;
        #pragma unroll
        for (int r = 0; r < 4; ++r) {
            int row = m0 + w * 16 + quad * 4 + r;
            x2[row * CC + col] = acc[c][r] + bias[col] + x_in[row * CC + col];
        }
    }
}

// ---------------- fc1: t2 @ w_fc1T + b_fc1, GELU -> h1 (bf16) --------------
__global__ void fc1_kernel(const short* __restrict__ t2, const short* __restrict__ wT,
                           const float* __restrict__ bias, short* __restrict__ h1)
{
    __shared__ short lds[2 * 64 * GSTRIDE];
    f32x4 acc[4];
    const int m0 = blockIdx.y * 64, n0 = blockIdx.x * 64;
    mfma_gemm_core<256>(t2, wT, m0, n0, acc, lds);
    const int lane = threadIdx.x & 63, w = threadIdx.x >> 6;
    const int quad = lane >> 4, l15 = lane & 15;
    #pragma unroll
    for (int c = 0; c < 4; ++c) {
        int col = n0 + c * 16 + l15;
        #pragma unroll
        for (int r = 0; r < 4; ++r) {
            int row = m0 + w * 16 + quad * 4 + r;
            float v = acc[c][r] + bias[col];
            float ge = 0.5f * v * (1.0f + erff(v * 0.7071067811865476f));
            h1[row * HID + col] = f2b(ge);
        }
    }
}

// ---------------- fc2: h1 @ w_fc2T + b_fc2 + x2 -> out (fp32) --------------
__global__ void fc2_kernel(const short* __restrict__ h1, const short* __restrict__ wT,
                           const float* __restrict__ bias, const float* __restrict__ x2,
                           float* __restrict__ out)
{
    __shared__ short lds[2 * 64 * GSTRIDE];
    f32x4 acc[4];
    const int m0 = blockIdx.y * 64, n0 = blockIdx.x * 64;
    mfma_gemm_core<1024>(h1, wT, m0, n0, acc, lds);
    const int lane = threadIdx.x & 63, w = threadIdx.x >> 6;
    const int quad = lane >> 4, l15 = lane & 15;
    #pragma unroll
    for (int c = 0; c < 4; ++c) {
        int col = n0 + c * 16 + l15;
        #pragma unroll
        for (int r = 0; r < 4; ++r) {
            int row = m0 + w * 16 + quad * 4 + r;
            out[row * CC + col] = acc[c][r] + bias[col] + x2[row * CC + col];
        }
    }
}

extern "C" void kernel_launch(void* const* d_in, const int* in_sizes, int n_in,
                              void* d_out, int out_size, void* d_ws, size_t ws_size,
                              hipStream_t stream)
{
    const float* x          = (const float*)d_in[0];
    const float* gamma1     = (const float*)d_in[1];
    const float* beta1      = (const float*)d_in[2];
    const float* w_qkv      = (const float*)d_in[3];
    const float* w_proj     = (const float*)d_in[4];
    const float* b_proj     = (const float*)d_in[5];
    const float* bias_table = (const float*)d_in[6];
    const float* gamma2     = (const float*)d_in[7];
    const float* beta2      = (const float*)d_in[8];
    const float* w_fc1      = (const float*)d_in[9];
    const float* b_fc1      = (const float*)d_in[10];
    const float* w_fc2      = (const float*)d_in[11];
    const float* b_fc2      = (const float*)d_in[12];
    // d_in[13] = rel_idx (int32) — unused: bias index computed analytically.

    short* S = (short*)d_ws;
    const int NC = NN * CC;               // 589824
    short* t1     = S;                    // bf16 [N][C]
    short* qb     = t1  + NC;             // bf16 [h][n][d]
    short* kb     = qb  + NC;             // bf16 [h][n][d]
    short* vT     = kb  + NC;             // bf16 [h][d][n]
    short* obuf   = vT  + NC;             // bf16 [N][C]
    short* t2     = obuf+ NC;             // bf16 [N][C]
    short* h1     = t2  + NC;             // bf16 [N][HID]
    short* wTqkv  = h1  + NN * HID;       // bf16 [768][256]
    short* wTproj = wTqkv  + 768 * 256;   // bf16 [256][256]
    short* wTfc1  = wTproj + 256 * 256;   // bf16 [1024][256]
    short* wTfc2  = wTfc1  + 1024 * 256;  // bf16 [256][1024]
    float* biasF  = (float*)(wTfc2 + 256 * 1024);      // f32 [NH][9025] (*LOG2E)
    float* x2     = biasF + NH * NBIAS;                // fp32 [N][C]
    float* Opart  = x2 + NC;                           // fp32 [NSPLIT][N][C]
    float* lpart  = Opart + NSPLIT * NC;               // fp32 [NSPLIT][NH][N]

    prep_kernel<<<NN + 512, 256, 0, stream>>>(x, gamma1, beta1, t1,
                                              w_qkv, w_proj, w_fc1, w_fc2, bias_table,
                                              wTqkv, wTproj, wTfc1, wTfc2, biasF);
    qkv_kernel<<<dim3(12, 36), 256, 0, stream>>>(t1, wTqkv, qb, kb, vT);
    attn_kernel<<<NSPLIT * 1152, 256, 0, stream>>>(qb, kb, vT, biasF, Opart, lpart);
    attn_norm_kernel<<<NN, 256, 0, stream>>>(Opart, lpart, obuf);
    proj_kernel<<<dim3(4, 36), 256, 0, stream>>>(obuf, wTproj, b_proj, x, x2);
    ln_kernel<<<NN, 256, 0, stream>>>(x2, gamma2, beta2, t2);
    fc1_kernel<<<dim3(16, 36), 256, 0, stream>>>(t2, wTfc1, b_fc1, h1);
    fc2_kernel<<<dim3(4, 36), 256, 0, stream>>>(h1, wTfc2, b_fc2, x2,
                                                (float*)d_out);
}

// Round 5
// 181.482 us; speedup vs baseline: 1.0409x; 1.0254x over previous
//
#include <hip/hip_runtime.h>
#include <hip/hip_bf16.h>
#include <math.h>

#define IH 48
#define IW 48
#define NN 2304          // N = IH*IW
#define CC 256           // channels
#define NH 8
#define HD 32
#define HID 1024
#define NBIAS 9025       // (2*48-1)^2
#define SCALE 0.17677669529663687f
#define LOG2E 1.4426950408889634f
#define LN_EPS 1e-5f
#define NSPLIT 3         // attention key-split factor (TLP: 3456 blocks)

typedef __attribute__((ext_vector_type(8))) short bf16x8;   // 8 bf16 in 4 VGPRs
typedef __attribute__((ext_vector_type(4))) short bf16x4;   // 4 bf16 in 2 VGPRs
typedef __attribute__((ext_vector_type(4))) float f32x4;

__device__ __forceinline__ short f2b(float f) {
    __hip_bfloat16 h = __float2bfloat16(f);
    short s; __builtin_memcpy(&s, &h, 2); return s;
}
__device__ __forceinline__ float b2f(short s) {
    __hip_bfloat16 h; __builtin_memcpy(&h, &s, 2); return __bfloat162float(h);
}
__device__ __forceinline__ float fast_exp2(float x) {
#if __has_builtin(__builtin_amdgcn_exp2f)
    return __builtin_amdgcn_exp2f(x);     // single v_exp_f32
#else
    return exp2f(x);
#endif
}

// ------- Prep: ln1 (blocks 0..NN-1) + weight/bias conversion ---------------
// bias table -> f32, pre-multiplied by LOG2E (attn adds it pre-exp2, no cvt).
__global__ void prep_kernel(const float* __restrict__ x, const float* __restrict__ g,
                            const float* __restrict__ b, short* __restrict__ t1,
                            const float* __restrict__ w_qkv, const float* __restrict__ w_proj,
                            const float* __restrict__ w_fc1, const float* __restrict__ w_fc2,
                            const float* __restrict__ bt,
                            short* __restrict__ o_qkv, short* __restrict__ o_proj,
                            short* __restrict__ o_fc1, short* __restrict__ o_fc2,
                            float* __restrict__ o_bias)
{
    const int bid = blockIdx.x, tid = threadIdx.x;
    if (bid < NN) {        // ---- LayerNorm row ----
        __shared__ float red[8];
        float v = x[bid * CC + tid];
        float s = v, s2 = v * v;
        #pragma unroll
        for (int off = 32; off > 0; off >>= 1) {
            s  += __shfl_xor(s, off);
            s2 += __shfl_xor(s2, off);
        }
        const int wid = tid >> 6;
        if ((tid & 63) == 0) { red[wid * 2] = s; red[wid * 2 + 1] = s2; }
        __syncthreads();
        float tot  = red[0] + red[2] + red[4] + red[6];
        float tot2 = red[1] + red[3] + red[5] + red[7];
        float mu   = tot * (1.0f / CC);
        float var  = tot2 * (1.0f / CC) - mu * mu;
        float rstd = rsqrtf(var + LN_EPS);
        t1[bid * CC + tid] = f2b((v - mu) * rstd * g[tid] + b[tid]);
        return;
    }
    // ---- weight conversions, flat grid-stride over 858632 elements ----
    const int stride = (gridDim.x - NN) * 256;
    for (int i = (bid - NN) * 256 + tid; i < 858632; i += stride) {
        int j = i;
        if (j < 196608)            { int n = j >> 8,  k = j & 255;  o_qkv [j] = f2b(w_qkv [k * 768  + n]); }
        else if ((j -= 196608) < 65536)  { int n = j >> 8,  k = j & 255;  o_proj[j] = f2b(w_proj[k * 256  + n]); }
        else if ((j -= 65536)  < 262144) { int n = j >> 8,  k = j & 255;  o_fc1 [j] = f2b(w_fc1 [k * 1024 + n]); }
        else if ((j -= 262144) < 262144) { int n = j >> 10, k = j & 1023; o_fc2 [j] = f2b(w_fc2 [k * 256  + n]); }
        else { j -= 262144; int h = j / NBIAS, idx = j - h * NBIAS; o_bias[j] = bt[idx * NH + h] * LOG2E; }
    }
}

// ---------------- LayerNorm (standalone, for ln2) --------------------------
__global__ void ln_kernel(const float* __restrict__ x,
                          const float* __restrict__ g,
                          const float* __restrict__ b,
                          short* __restrict__ out)
{
    __shared__ float red[8];
    const int row = blockIdx.x, tid = threadIdx.x;
    float v = x[row * CC + tid];
    float s = v, s2 = v * v;
    #pragma unroll
    for (int off = 32; off > 0; off >>= 1) {
        s  += __shfl_xor(s, off);
        s2 += __shfl_xor(s2, off);
    }
    const int wid = tid >> 6;
    if ((tid & 63) == 0) { red[wid * 2] = s; red[wid * 2 + 1] = s2; }
    __syncthreads();
    float tot  = red[0] + red[2] + red[4] + red[6];
    float tot2 = red[1] + red[3] + red[5] + red[7];
    float mu   = tot * (1.0f / CC);
    float var  = tot2 * (1.0f / CC) - mu * mu;
    float rstd = rsqrtf(var + LN_EPS);
    out[row * CC + tid] = f2b((v - mu) * rstd * g[tid] + b[tid]);
}

// --- MFMA GEMM core: 64x64 tile, 4 waves, K-step 64, register-pipelined ----
#define GSTRIDE 72
template<int K>
__device__ __forceinline__ void mfma_gemm_core(const short* __restrict__ A,
                                               const short* __restrict__ BT,
                                               int m0, int n0, f32x4 acc[4],
                                               short* lds)
{
    short* As = lds;                 // [64][72]
    short* Bs = lds + 64 * GSTRIDE;  // [64][72]
    const int tid  = threadIdx.x;
    const int w    = tid >> 6, lane = tid & 63;
    const int quad = lane >> 4, l15 = lane & 15;
    const int sr = tid >> 2;            // staging row 0..63
    const int sc = (tid & 3) * 16;      // k-granule 0,16,32,48
    #pragma unroll
    for (int c = 0; c < 4; ++c) acc[c] = (f32x4){0.f, 0.f, 0.f, 0.f};

    const short* Ap = &A [(m0 + sr) * K + sc];
    const short* Bp = &BT[(n0 + sr) * K + sc];
    bf16x8 ra0 = *(const bf16x8*)Ap,       ra1 = *(const bf16x8*)(Ap + 8);
    bf16x8 rb0 = *(const bf16x8*)Bp,       rb1 = *(const bf16x8*)(Bp + 8);

    for (int k0 = 0; k0 < K; k0 += 64) {
        __syncthreads();                       // LDS consumers of tile k-1 done
        *(bf16x8*)&As[sr * GSTRIDE + sc]     = ra0;
        *(bf16x8*)&As[sr * GSTRIDE + sc + 8] = ra1;
        *(bf16x8*)&Bs[sr * GSTRIDE + sc]     = rb0;
        *(bf16x8*)&Bs[sr * GSTRIDE + sc + 8] = rb1;
        if (k0 + 64 < K) {                     // prefetch tile k+1 (overlaps below)
            ra0 = *(const bf16x8*)(Ap + k0 + 64);
            ra1 = *(const bf16x8*)(Ap + k0 + 72);
            rb0 = *(const bf16x8*)(Bp + k0 + 64);
            rb1 = *(const bf16x8*)(Bp + k0 + 72);
        }
        __syncthreads();                       // tile k visible
        #pragma unroll
        for (int s = 0; s < 2; ++s) {
            bf16x8 a = *(const bf16x8*)&As[(w * 16 + l15) * GSTRIDE + s * 32 + quad * 8];
            #pragma unroll
            for (int c = 0; c < 4; ++c) {
                bf16x8 b = *(const bf16x8*)&Bs[(c * 16 + l15) * GSTRIDE + s * 32 + quad * 8];
                acc[c] = __builtin_amdgcn_mfma_f32_16x16x32_bf16(a, b, acc[c], 0, 0, 0);
            }
        }
    }
}
// C/D layout [m89]: col = n-tile*16 + (lane&15), row = 16w + quad*4 + reg.

// ---------------- QKV: t1 @ w_qkvT -> qb, kb (bf16 [h][n][d]), vT [h][d][n]-
// q is pre-scaled by SCALE*LOG2E so attention softmax can use exp2 directly.
__global__ void qkv_kernel(const short* __restrict__ t1, const short* __restrict__ wT,
                           short* __restrict__ qb, short* __restrict__ kb,
                           short* __restrict__ vT)
{
    __shared__ short lds[2 * 64 * GSTRIDE];
    f32x4 acc[4];
    const int m0 = blockIdx.y * 64, n0 = blockIdx.x * 64;
    mfma_gemm_core<256>(t1, wT, m0, n0, acc, lds);
    const int lane = threadIdx.x & 63, w = threadIdx.x >> 6;
    const int quad = lane >> 4, l15 = lane & 15;
    #pragma unroll
    for (int c = 0; c < 4; ++c) {
        int col = n0 + c * 16 + l15;
        int three = col >> 8, rem = col & 255;
        int h = rem >> 5, d = rem & 31;
        #pragma unroll
        for (int r = 0; r < 4; ++r) {
            int row = m0 + w * 16 + quad * 4 + r;
            float v = acc[c][r];
            if (three == 0)      qb[(h * NN + row) * HD + d] = f2b(v * (SCALE * LOG2E));
            else if (three == 1) kb[(h * NN + row) * HD + d] = f2b(v);
            else                 vT[(h * HD + d) * NN + row] = f2b(v);
        }
    }
}

// -------- MFMA flash attention: swapped-QK, register-resident P ------------
// mfma(K,Q) -> lane holds P^T[key=quad*4+r][q=l15]. PV contraction slots are
// permuted so each lane's 8 P values ARE its PV A-fragment (no LDS, no
// cross-lane moves). V B-fragment loads with the same permutation.
// Round-4 lesson: occupancy 33->66% moved dur only -11% -> shared-resource
// saturation: 8 address-DIVERGENT 4B bias gathers/iter serialize the per-CU
// vector-memory address pipe. Fix: block's bias needs form a 16x63 window of
// the table (qi fixed, 16-wide qj, 16 key rows) -> stage 4KB into LDS
// coalesced once per block; inner loop reads bias via the (idle) DS pipe.
__global__ __launch_bounds__(256) void attn_kernel(
        const short* __restrict__ qb, const short* __restrict__ kb,
        const short* __restrict__ vT, const float* __restrict__ biasF,
        float* __restrict__ Opart, float* __restrict__ lpart)
{
    __shared__ float Ored[4][16][33];
    __shared__ float lred[4][16];
    __shared__ float bias_lds[16][64];   // rows: key img-row; cols: qj-kj+47-qj0
    const int w = threadIdx.x >> 6, lane = threadIdx.x & 63;
    const int quad = lane >> 4, l15 = lane & 15;
    const int sp = blockIdx.x / 1152;             // key-split index 0..2
    const int bb = blockIdx.x - sp * 1152;
    const int h = bb / 144, q0 = (bb % 144) * 16;
    const int t0 = sp * 768 + w * 192;
    const float* bt = &biasF[h * NBIAS];

    // per-block q coords: 16-wide q-tiles never straddle image rows (16 | 48)
    const int qi = q0 / IW, qj0 = q0 % IW;

    // ---- stage the 16x63 bias window (keys sp*16..sp*16+15 image rows) ----
    for (int idx = threadIdx.x; idx < 16 * 63; idx += 256) {
        int kr = idx / 63, cc = idx - kr * 63;
        bias_lds[kr][cc] = bt[(qi - (sp * 16 + kr) + 47) * 95 + qj0 + cc];
    }

    // Q fragment: B[n=q=l15][k=quad*8+j]  (q pre-scaled by SCALE*LOG2E)
    bf16x8 qf = *(const bf16x8*)&qb[(h * NN + q0 + l15) * HD + quad * 8];

    __syncthreads();                     // bias window visible

    f32x4 O0 = (f32x4){0.f,0.f,0.f,0.f}, O1 = (f32x4){0.f,0.f,0.f,0.f};
    float lp = 0.f;
    const f32x4 zero = (f32x4){0.f,0.f,0.f,0.f};

    for (int c = 0; c < 6; ++c) {
        const int t = t0 + c * 32;
        bf16x8 k0f = *(const bf16x8*)&kb[(h * NN + t      + l15) * HD + quad * 8];
        bf16x8 k1f = *(const bf16x8*)&kb[(h * NN + t + 16 + l15) * HD + quad * 8];
        // V with permuted key slots: dim=l15 (O0) / 16+l15 (O1)
        const short* vp0 = &vT[(h * HD + l15)      * NN + t + quad * 4];
        const short* vp1 = &vT[(h * HD + 16 + l15) * NN + t + quad * 4];
        bf16x4 va0 = *(const bf16x4*)vp0, vb0 = *(const bf16x4*)(vp0 + 16);
        bf16x4 va1 = *(const bf16x4*)vp1, vb1 = *(const bf16x4*)(vp1 + 16);

        f32x4 s0 = __builtin_amdgcn_mfma_f32_16x16x32_bf16(k0f, qf, zero, 0, 0, 0);
        f32x4 s1 = __builtin_amdgcn_mfma_f32_16x16x32_bf16(k1f, qf, zero, 0, 0, 0);

        // bias from LDS: 4-aligned key groups never straddle image rows (4|48)
        const int kA = t + quad * 4, kB = kA + 16;
        const int kiA = kA / IW, kjA = kA - kiA * IW;
        const int kiB = kB / IW, kjB = kB - kiB * IW;
        const float* pA = &bias_lds[kiA - sp * 16][l15 + 47 - kjA];
        const float* pB = &bias_lds[kiB - sp * 16][l15 + 47 - kjB];

        float p[8];
        #pragma unroll
        for (int r = 0; r < 4; ++r) {
            p[r]     = fast_exp2(s0[r] + pA[-r]);
            p[4 + r] = fast_exp2(s1[r] + pB[-r]);
        }
        #pragma unroll
        for (int r = 0; r < 8; ++r) lp += p[r];
        bf16x8 pa = (bf16x8){ f2b(p[0]), f2b(p[1]), f2b(p[2]), f2b(p[3]),
                              f2b(p[4]), f2b(p[5]), f2b(p[6]), f2b(p[7]) };
        bf16x8 v0 = (bf16x8){ va0[0], va0[1], va0[2], va0[3],
                              vb0[0], vb0[1], vb0[2], vb0[3] };
        bf16x8 v1 = (bf16x8){ va1[0], va1[1], va1[2], va1[3],
                              vb1[0], vb1[1], vb1[2], vb1[3] };
        O0 = __builtin_amdgcn_mfma_f32_16x16x32_bf16(pa, v0, O0, 0, 0, 0);
        O1 = __builtin_amdgcn_mfma_f32_16x16x32_bf16(pa, v1, O1, 0, 0, 0);
    }

    // lp is per-lane (q=l15): reduce across the 4 quad-lanes sharing l15
    lp += __shfl_xor(lp, 16);
    lp += __shfl_xor(lp, 32);
    if (quad == 0) lred[w][l15] = lp;
    // O: row = q = quad*4+r, col = dim = l15 (O0) / 16+l15 (O1)
    #pragma unroll
    for (int r = 0; r < 4; ++r) {
        Ored[w][quad * 4 + r][l15]      = O0[r];
        Ored[w][quad * 4 + r][16 + l15] = O1[r];
    }
    __syncthreads();
    {   // 256 threads combine 16 q-rows x 32 dims -> fp32 partials
        const int col = threadIdx.x & 31;
        for (int rr = threadIdx.x >> 5; rr < 16; rr += 8) {
            float s = 0.f, l = 0.f;
            #pragma unroll
            for (int pw = 0; pw < 4; ++pw) { s += Ored[pw][rr][col]; l += lred[pw][rr]; }
            Opart[sp * (NN * CC) + (q0 + rr) * CC + h * HD + col] = s;
            if (col == 0) lpart[(sp * NH + h) * NN + q0 + rr] = l;
        }
    }
}

// ------- combine key-split partials: obuf = (sum O) / (sum l), bf16 --------
__global__ void attn_norm_kernel(const float* __restrict__ Opart,
                                 const float* __restrict__ lpart,
                                 short* __restrict__ obuf)
{
    const int n = blockIdx.x, c = threadIdx.x, h = c >> 5;
    float v = Opart[n * CC + c] + Opart[NN * CC + n * CC + c]
            + Opart[2 * NN * CC + n * CC + c];
    float l = lpart[h * NN + n] + lpart[(NH + h) * NN + n]
            + lpart[(2 * NH + h) * NN + n];
    obuf[n * CC + c] = f2b(v / l);
}

// ---------------- proj: o @ w_projT + b_proj + x -> x2 (fp32) --------------
__global__ void proj_kernel(const short* __restrict__ o, const short* __restrict__ wT,
                            const float* __restrict__ bias, const float* __restrict__ x_in,
                            float* __restrict__ x2)
{
    __shared__ short lds[2 * 64 * GSTRIDE];
    f32x4 acc[4];
    const int m0 = blockIdx.y * 64, n0 = blockIdx.x * 64;
    mfma_gemm_core<256>(o, wT, m0, n0, acc, lds);
    const int lane = threadIdx.x & 63, w = threadIdx.x >> 6;
    const int quad = lane >> 4, l15 = lane & 15;
    #pragma unroll
    for (int c = 0; c < 4; ++c) {
        int col = n0 + c * 16 + l15;
        #pragma unroll
        for (int r = 0; r < 4; ++r) {
            int row = m0 + w * 16 + quad * 4 + r;
            x2[row * CC + col] = acc[c][r] + bias[col] + x_in[row * CC + col];
        }
    }
}

// ---------------- fc1: t2 @ w_fc1T + b_fc1, GELU -> h1 (bf16) --------------
__global__ void fc1_kernel(const short* __restrict__ t2, const short* __restrict__ wT,
                           const float* __restrict__ bias, short* __restrict__ h1)
{
    __shared__ short lds[2 * 64 * GSTRIDE];
    f32x4 acc[4];
    const int m0 = blockIdx.y * 64, n0 = blockIdx.x * 64;
    mfma_gemm_core<256>(t2, wT, m0, n0, acc, lds);
    const int lane = threadIdx.x & 63, w = threadIdx.x >> 6;
    const int quad = lane >> 4, l15 = lane & 15;
    #pragma unroll
    for (int c = 0; c < 4; ++c) {
        int col = n0 + c * 16 + l15;
        #pragma unroll
        for (int r = 0; r < 4; ++r) {
            int row = m0 + w * 16 + quad * 4 + r;
            float v = acc[c][r] + bias[col];
            float ge = 0.5f * v * (1.0f + erff(v * 0.7071067811865476f));
            h1[row * HID + col] = f2b(ge);
        }
    }
}

// ---------------- fc2: h1 @ w_fc2T + b_fc2 + x2 -> out (fp32) --------------
__global__ void fc2_kernel(const short* __restrict__ h1, const short* __restrict__ wT,
                           const float* __restrict__ bias, const float* __restrict__ x2,
                           float* __restrict__ out)
{
    __shared__ short lds[2 * 64 * GSTRIDE];
    f32x4 acc[4];
    const int m0 = blockIdx.y * 64, n0 = blockIdx.x * 64;
    mfma_gemm_core<1024>(h1, wT, m0, n0, acc, lds);
    const int lane = threadIdx.x & 63, w = threadIdx.x >> 6;
    const int quad = lane >> 4, l15 = lane & 15;
    #pragma unroll
    for (int c = 0; c < 4; ++c) {
        int col = n0 + c * 16 + l15;
        #pragma unroll
        for (int r = 0; r < 4; ++r) {
            int row = m0 + w * 16 + quad * 4 + r;
            out[row * CC + col] = acc[c][r] + bias[col] + x2[row * CC + col];
        }
    }
}

extern "C" void kernel_launch(void* const* d_in, const int* in_sizes, int n_in,
                              void* d_out, int out_size, void* d_ws, size_t ws_size,
                              hipStream_t stream)
{
    const float* x          = (const float*)d_in[0];
    const float* gamma1     = (const float*)d_in[1];
    const float* beta1      = (const float*)d_in[2];
    const float* w_qkv      = (const float*)d_in[3];
    const float* w_proj     = (const float*)d_in[4];
    const float* b_proj     = (const float*)d_in[5];
    const float* bias_table = (const float*)d_in[6];
    const float* gamma2     = (const float*)d_in[7];
    const float* beta2      = (const float*)d_in[8];
    const float* w_fc1      = (const float*)d_in[9];
    const float* b_fc1      = (const float*)d_in[10];
    const float* w_fc2      = (const float*)d_in[11];
    const float* b_fc2      = (const float*)d_in[12];
    // d_in[13] = rel_idx (int32) — unused: bias index computed analytically.

    short* S = (short*)d_ws;
    const int NC = NN * CC;               // 589824
    short* t1     = S;                    // bf16 [N][C]
    short* qb     = t1  + NC;             // bf16 [h][n][d]
    short* kb     = qb  + NC;             // bf16 [h][n][d]
    short* vT     = kb  + NC;             // bf16 [h][d][n]
    short* obuf   = vT  + NC;             // bf16 [N][C]
    short* t2     = obuf+ NC;             // bf16 [N][C]
    short* h1     = t2  + NC;             // bf16 [N][HID]
    short* wTqkv  = h1  + NN * HID;       // bf16 [768][256]
    short* wTproj = wTqkv  + 768 * 256;   // bf16 [256][256]
    short* wTfc1  = wTproj + 256 * 256;   // bf16 [1024][256]
    short* wTfc2  = wTfc1  + 1024 * 256;  // bf16 [256][1024]
    float* biasF  = (float*)(wTfc2 + 256 * 1024);      // f32 [NH][9025] (*LOG2E)
    float* x2     = biasF + NH * NBIAS;                // fp32 [N][C]
    float* Opart  = x2 + NC;                           // fp32 [NSPLIT][N][C]
    float* lpart  = Opart + NSPLIT * NC;               // fp32 [NSPLIT][NH][N]

    prep_kernel<<<NN + 512, 256, 0, stream>>>(x, gamma1, beta1, t1,
                                              w_qkv, w_proj, w_fc1, w_fc2, bias_table,
                                              wTqkv, wTproj, wTfc1, wTfc2, biasF);
    qkv_kernel<<<dim3(12, 36), 256, 0, stream>>>(t1, wTqkv, qb, kb, vT);
    attn_kernel<<<NSPLIT * 1152, 256, 0, stream>>>(qb, kb, vT, biasF, Opart, lpart);
    attn_norm_kernel<<<NN, 256, 0, stream>>>(Opart, lpart, obuf);
    proj_kernel<<<dim3(4, 36), 256, 0, stream>>>(obuf, wTproj, b_proj, x, x2);
    ln_kernel<<<NN, 256, 0, stream>>>(x2, gamma2, beta2, t2);
    fc1_kernel<<<dim3(16, 36), 256, 0, stream>>>(t2, wTfc1, b_fc1, h1);
    fc2_kernel<<<dim3(4, 36), 256, 0, stream>>>(h1, wTfc2, b_fc2, x2,
                                                (float*)d_out);
}

// Round 7
// 169.058 us; speedup vs baseline: 1.1174x; 1.0735x over previous
//
#include <hip/hip_runtime.h>
#include <hip/hip_bf16.h>
#include <math.h>

#define IH 48
#define IW 48
#define NN 2304          // N = IH*IW
#define CC 256           // channels
#define NH 8
#define HD 32
#define HID 1024
#define NBIAS 9025       // (2*48-1)^2
#define SCALE 0.17677669529663687f
#define LOG2E 1.4426950408889634f
#define LN_EPS 1e-5f

typedef __attribute__((ext_vector_type(8))) short bf16x8;   // 8 bf16 in 4 VGPRs
typedef __attribute__((ext_vector_type(4))) float f32x4;

__device__ __forceinline__ short f2b(float f) {
    __hip_bfloat16 h = __float2bfloat16(f);
    short s; __builtin_memcpy(&s, &h, 2); return s;
}
__device__ __forceinline__ float b2f(short s) {
    __hip_bfloat16 h; __builtin_memcpy(&h, &s, 2); return __bfloat162float(h);
}
__device__ __forceinline__ float fast_exp2(float x) {
#if __has_builtin(__builtin_amdgcn_exp2f)
    return __builtin_amdgcn_exp2f(x);     // single v_exp_f32
#else
    return exp2f(x);
#endif
}

// ------- Prep: ln1 (blocks 0..NN-1) + bias-table conversion ----------------
// bias table is pre-multiplied by LOG2E so attention can use exp2 directly.
// Weight transposes moved to wtrans_kernel (coalesced LDS tiles).
__global__ void prep_kernel(const float* __restrict__ x, const float* __restrict__ g,
                            const float* __restrict__ b, short* __restrict__ t1,
                            const float* __restrict__ bt, short* __restrict__ o_bias)
{
    const int bid = blockIdx.x, tid = threadIdx.x;
    if (bid < NN) {        // ---- LayerNorm row ----
        __shared__ float red[8];
        float v = x[bid * CC + tid];
        float s = v, s2 = v * v;
        #pragma unroll
        for (int off = 32; off > 0; off >>= 1) {
            s  += __shfl_xor(s, off);
            s2 += __shfl_xor(s2, off);
        }
        const int wid = tid >> 6;
        if ((tid & 63) == 0) { red[wid * 2] = s; red[wid * 2 + 1] = s2; }
        __syncthreads();
        float tot  = red[0] + red[2] + red[4] + red[6];
        float tot2 = red[1] + red[3] + red[5] + red[7];
        float mu   = tot * (1.0f / CC);
        float var  = tot2 * (1.0f / CC) - mu * mu;
        float rstd = rsqrtf(var + LN_EPS);
        t1[bid * CC + tid] = f2b((v - mu) * rstd * g[tid] + b[tid]);
        return;
    }
    // ---- bias table: [9025][8] f32 -> [8][9025] bf16, read-coalesced ----
    const int stride = (gridDim.x - NN) * 256;
    for (int i = (bid - NN) * 256 + tid; i < NBIAS * NH; i += stride) {
        int idx = i >> 3, h = i & 7;
        o_bias[h * NBIAS + idx] = f2b(bt[i] * LOG2E);
    }
}

// ------- Weight transpose: f32 [K][N] -> bf16 [N][K], 32x32 LDS tiles ------
// Round-5 lesson: prep's transposing gathers were stride-768/1024 4B reads
// (uncoalesced). Tiled transpose makes both sides coalesced.
__global__ void wtrans_kernel(const float* __restrict__ w_qkv, const float* __restrict__ w_proj,
                              const float* __restrict__ w_fc1, const float* __restrict__ w_fc2,
                              short* __restrict__ o_qkv, short* __restrict__ o_proj,
                              short* __restrict__ o_fc1, short* __restrict__ o_fc2)
{
    __shared__ float t[32][33];
    int b = blockIdx.x;
    const float* src; short* dst; int K, Nn, kt, nt;
    if (b < 192)      { src = w_qkv;  dst = o_qkv;  K = 256;  Nn = 768;  kt = b / 24; nt = b % 24; }
    else if (b < 256) { b -= 192; src = w_proj; dst = o_proj; K = 256;  Nn = 256;  kt = b / 8;  nt = b % 8; }
    else if (b < 512) { b -= 256; src = w_fc1;  dst = o_fc1;  K = 256;  Nn = 1024; kt = b / 32; nt = b % 32; }
    else              { b -= 512; src = w_fc2;  dst = o_fc2;  K = 1024; Nn = 256;  kt = b / 8;  nt = b % 8; }
    const int r = threadIdx.x >> 5, c = threadIdx.x & 31;
    const int k0 = kt * 32, n0 = nt * 32;
    #pragma unroll
    for (int i = 0; i < 4; ++i)
        t[r + i * 8][c] = src[(k0 + r + i * 8) * Nn + n0 + c];
    __syncthreads();
    #pragma unroll
    for (int i = 0; i < 4; ++i)
        dst[(n0 + r + i * 8) * K + k0 + c] = f2b(t[c][r + i * 8]);
}

// ------- LayerNorm2 fused with proj split-K reduce + residual --------------
// v = proj_p0 + proj_p1 + b_proj + x ; x2 = v ; t2 = LN(v)
__global__ void ln_kernel(const float* __restrict__ p0, const float* __restrict__ p1,
                          const float* __restrict__ bp, const float* __restrict__ x_in,
                          const float* __restrict__ g, const float* __restrict__ b,
                          short* __restrict__ t2, float* __restrict__ x2)
{
    __shared__ float red[8];
    const int row = blockIdx.x, tid = threadIdx.x;
    const int i = row * CC + tid;
    float v = p0[i] + p1[i] + bp[tid] + x_in[i];
    x2[i] = v;
    float s = v, s2 = v * v;
    #pragma unroll
    for (int off = 32; off > 0; off >>= 1) {
        s  += __shfl_xor(s, off);
        s2 += __shfl_xor(s2, off);
    }
    const int wid = tid >> 6;
    if ((tid & 63) == 0) { red[wid * 2] = s; red[wid * 2 + 1] = s2; }
    __syncthreads();
    float tot  = red[0] + red[2] + red[4] + red[6];
    float tot2 = red[1] + red[3] + red[5] + red[7];
    float mu   = tot * (1.0f / CC);
    float var  = tot2 * (1.0f / CC) - mu * mu;
    float rstd = rsqrtf(var + LN_EPS);
    t2[i] = f2b((v - mu) * rstd * g[tid] + b[tid]);
}

// --- MFMA GEMM core: 64x64 tile, 4 waves, K-step 64, register-pipelined ----
// KLEN = K range this block covers (starting at kb), KSTR = row stride.
#define GSTRIDE 72
template<int KLEN, int KSTR>
__device__ __forceinline__ void mfma_gemm_core(const short* __restrict__ A,
                                               const short* __restrict__ BT,
                                               int m0, int n0, int kb, f32x4 acc[4],
                                               short* lds)
{
    short* As = lds;                 // [64][72]
    short* Bs = lds + 64 * GSTRIDE;  // [64][72]
    const int tid  = threadIdx.x;
    const int w    = tid >> 6, lane = tid & 63;
    const int quad = lane >> 4, l15 = lane & 15;
    const int sr = tid >> 2;            // staging row 0..63
    const int sc = (tid & 3) * 16;      // k-granule 0,16,32,48
    #pragma unroll
    for (int c = 0; c < 4; ++c) acc[c] = (f32x4){0.f, 0.f, 0.f, 0.f};

    const short* Ap = &A [(m0 + sr) * KSTR + kb + sc];
    const short* Bp = &BT[(n0 + sr) * KSTR + kb + sc];
    bf16x8 ra0 = *(const bf16x8*)Ap,       ra1 = *(const bf16x8*)(Ap + 8);
    bf16x8 rb0 = *(const bf16x8*)Bp,       rb1 = *(const bf16x8*)(Bp + 8);

    for (int k0 = 0; k0 < KLEN; k0 += 64) {
        __syncthreads();                       // LDS consumers of tile k-1 done
        *(bf16x8*)&As[sr * GSTRIDE + sc]     = ra0;
        *(bf16x8*)&As[sr * GSTRIDE + sc + 8] = ra1;
        *(bf16x8*)&Bs[sr * GSTRIDE + sc]     = rb0;
        *(bf16x8*)&Bs[sr * GSTRIDE + sc + 8] = rb1;
        if (k0 + 64 < KLEN) {                  // prefetch tile k+1 (overlaps below)
            ra0 = *(const bf16x8*)(Ap + k0 + 64);
            ra1 = *(const bf16x8*)(Ap + k0 + 72);
            rb0 = *(const bf16x8*)(Bp + k0 + 64);
            rb1 = *(const bf16x8*)(Bp + k0 + 72);
        }
        __syncthreads();                       // tile k visible
        #pragma unroll
        for (int s = 0; s < 2; ++s) {
            bf16x8 a = *(const bf16x8*)&As[(w * 16 + l15) * GSTRIDE + s * 32 + quad * 8];
            #pragma unroll
            for (int c = 0; c < 4; ++c) {
                bf16x8 b = *(const bf16x8*)&Bs[(c * 16 + l15) * GSTRIDE + s * 32 + quad * 8];
                acc[c] = __builtin_amdgcn_mfma_f32_16x16x32_bf16(a, b, acc[c], 0, 0, 0);
            }
        }
    }
}
// C/D layout [m89]: col = n-tile*16 + (lane&15), row = 16w + quad*4 + reg.

// ---------------- QKV: t1 @ w_qkvT -> qb, kb (bf16 [h][n][d]), vT [h][d][n]-
// q is pre-scaled by SCALE*LOG2E so attention softmax can use exp2 directly.
__global__ void qkv_kernel(const short* __restrict__ t1, const short* __restrict__ wT,
                           short* __restrict__ qb, short* __restrict__ kb,
                           short* __restrict__ vT)
{
    __shared__ short lds[2 * 64 * GSTRIDE];
    f32x4 acc[4];
    const int m0 = blockIdx.y * 64, n0 = blockIdx.x * 64;
    mfma_gemm_core<256, 256>(t1, wT, m0, n0, 0, acc, lds);
    const int lane = threadIdx.x & 63, w = threadIdx.x >> 6;
    const int quad = lane >> 4, l15 = lane & 15;
    #pragma unroll
    for (int c = 0; c < 4; ++c) {
        int col = n0 + c * 16 + l15;
        int three = col >> 8, rem = col & 255;
        int h = rem >> 5, d = rem & 31;
        #pragma unroll
        for (int r = 0; r < 4; ++r) {
            int row = m0 + w * 16 + quad * 4 + r;
            float v = acc[c][r];
            if (three == 0)      qb[(h * NN + row) * HD + d] = f2b(v * (SCALE * LOG2E));
            else if (three == 1) kb[(h * NN + row) * HD + d] = f2b(v);
            else                 vT[(h * HD + d) * NN + row] = f2b(v);
        }
    }
}

// -------- MFMA flash attention: round-1 structure (best measured: 42.3us) --
// block=(head,16q), 4 waves x 576 keys, P via per-wave LDS round-trip.
// Only change vs round-1: the 8 divergent bf16 bias gathers/iter are replaced
// by a 48x63 bf16 LDS window staged coalesced once per block (mechanism
// validated round 4->5). Rows: key img-row ki; col = quad*4+r+47-kj0-l15.
#define PSTRIDE 40    // sbuf row stride: 80 B (16B-aligned, conflict-free b128)
__global__ __launch_bounds__(256) void attn_kernel(
        const short* __restrict__ qb, const short* __restrict__ kb,
        const short* __restrict__ vT, const short* __restrict__ biasT,
        short* __restrict__ o)
{
    __shared__ float Ored[4][16][33];
    __shared__ float lred[4][16];
    __shared__ short sbuf[4][16 * PSTRIDE];
    __shared__ short bwin[48][64];
    const int w = threadIdx.x >> 6, lane = threadIdx.x & 63;
    const int quad = lane >> 4, l15 = lane & 15;
    const int h = blockIdx.x / 144, q0 = (blockIdx.x % 144) * 16;
    const int t0 = w * 576;
    short* sb = &sbuf[w][0];
    const short* bt = &biasT[h * NBIAS];

    // per-block q coords: 16-row q-tiles never straddle image rows (16 | 48)
    const int qi = q0 / IW, qj0 = q0 % IW;

    // ---- stage the 48x63 bias window, coalesced ----
    for (int idx = threadIdx.x; idx < 48 * 63; idx += 256) {
        int kr = idx / 63, cc = idx - kr * 63;
        bwin[kr][cc] = bt[(qi - kr + 47) * 95 + qj0 + cc];
    }

    // Q fragment: A[m=lane&15][k=quad*8+j]  (q pre-scaled by SCALE*LOG2E)
    bf16x8 qf = *(const bf16x8*)&qb[(h * NN + q0 + l15) * HD + quad * 8];

    f32x4 O0 = (f32x4){0.f,0.f,0.f,0.f}, O1 = (f32x4){0.f,0.f,0.f,0.f};
    float lp[4] = {0.f, 0.f, 0.f, 0.f};
    const f32x4 zero = (f32x4){0.f,0.f,0.f,0.f};

    __syncthreads();                       // bias window visible

    for (int c = 0; c < 18; ++c) {
        const int t = t0 + c * 32;
        bf16x8 k0f = *(const bf16x8*)&kb[(h * NN + t      + l15) * HD + quad * 8];
        bf16x8 k1f = *(const bf16x8*)&kb[(h * NN + t + 16 + l15) * HD + quad * 8];
        f32x4 s0 = __builtin_amdgcn_mfma_f32_16x16x32_bf16(qf, k0f, zero, 0, 0, 0);
        f32x4 s1 = __builtin_amdgcn_mfma_f32_16x16x32_bf16(qf, k1f, zero, 0, 0, 0);
        bf16x8 v0 = *(const bf16x8*)&vT[(h * HD + l15)      * NN + t + quad * 8];
        bf16x8 v1 = *(const bf16x8*)&vT[(h * HD + 16 + l15) * NN + t + quad * 8];

        // bias from LDS window: 16-key halves never straddle image rows
        const int ki0 = t / IW,        kj0_ = t - ki0 * IW;
        const int ki1 = (t + 16) / IW, kj1_ = (t + 16) - ki1 * IW;
        const int cA = quad * 4 + 47 - kj0_ - l15;
        const int cB = quad * 4 + 47 - kj1_ - l15;

        #pragma unroll
        for (int r = 0; r < 4; ++r) {
            float p0 = fast_exp2(s0[r] + b2f(bwin[ki0][cA + r]));
            float p1 = fast_exp2(s1[r] + b2f(bwin[ki1][cB + r]));
            lp[r] += p0 + p1;
            sb[(quad * 4 + r) * PSTRIDE + l15]      = f2b(p0);
            sb[(quad * 4 + r) * PSTRIDE + 16 + l15] = f2b(p1);
        }
        // Per-wave private LDS round-trip; DS pipe is in-order within a wave.
        asm volatile("s_waitcnt lgkmcnt(0)" ::: "memory");
        bf16x8 pa = *(const bf16x8*)&sb[l15 * PSTRIDE + quad * 8];
        O0 = __builtin_amdgcn_mfma_f32_16x16x32_bf16(pa, v0, O0, 0, 0, 0);
        O1 = __builtin_amdgcn_mfma_f32_16x16x32_bf16(pa, v1, O1, 0, 0, 0);
    }

    #pragma unroll
    for (int r = 0; r < 4; ++r) {
        float l = lp[r];
        l += __shfl_xor(l, 1); l += __shfl_xor(l, 2);
        l += __shfl_xor(l, 4); l += __shfl_xor(l, 8);
        if (l15 == 0) lred[w][quad * 4 + r] = l;
        Ored[w][quad * 4 + r][l15]      = O0[r];
        Ored[w][quad * 4 + r][16 + l15] = O1[r];
    }
    __syncthreads();
    {   // 256 threads combine 16 q-rows x 32 dims (2 rows per thread)
        const int col = threadIdx.x & 31;
        for (int rr = threadIdx.x >> 5; rr < 16; rr += 8) {
            float s = 0.f, l = 0.f;
            #pragma unroll
            for (int pw = 0; pw < 4; ++pw) { s += Ored[pw][rr][col]; l += lred[pw][rr]; }
            o[(q0 + rr) * CC + h * HD + col] = f2b(s / l);
        }
    }
}

// ------- proj: o @ w_projT, split-K x2 -> raw fp32 partials ----------------
// Reduce (+bias+residual) is fused into ln_kernel. Grid (4,36,2) = 288 blocks.
// Ppj ALIASES the dead t1|qb|kb|vT region (no extra workspace).
__global__ void proj_kernel(const short* __restrict__ o, const short* __restrict__ wT,
                            float* __restrict__ Ppj)
{
    __shared__ short lds[2 * 64 * GSTRIDE];
    f32x4 acc[4];
    const int m0 = blockIdx.y * 64, n0 = blockIdx.x * 64, z = blockIdx.z;
    mfma_gemm_core<128, 256>(o, wT, m0, n0, z * 128, acc, lds);
    const int lane = threadIdx.x & 63, w = threadIdx.x >> 6;
    const int quad = lane >> 4, l15 = lane & 15;
    float* out = Ppj + z * (NN * CC);
    #pragma unroll
    for (int c = 0; c < 4; ++c) {
        int col = n0 + c * 16 + l15;
        #pragma unroll
        for (int r = 0; r < 4; ++r) {
            int row = m0 + w * 16 + quad * 4 + r;
            out[row * CC + col] = acc[c][r];
        }
    }
}

// ---------------- fc1: t2 @ w_fc1T + b_fc1, GELU -> h1 (bf16) --------------
__global__ void fc1_kernel(const short* __restrict__ t2, const short* __restrict__ wT,
                           const float* __restrict__ bias, short* __restrict__ h1)
{
    __shared__ short lds[2 * 64 * GSTRIDE];
    f32x4 acc[4];
    const int m0 = blockIdx.y * 64, n0 = blockIdx.x * 64;
    mfma_gemm_core<256, 256>(t2, wT, m0, n0, 0, acc, lds);
    const int lane = threadIdx.x & 63, w = threadIdx.x >> 6;
    const int quad = lane >> 4, l15 = lane & 15;
    #pragma unroll
    for (int c = 0; c < 4; ++c) {
        int col = n0 + c * 16 + l15;
        #pragma unroll
        for (int r = 0; r < 4; ++r) {
            int row = m0 + w * 16 + quad * 4 + r;
            float v = acc[c][r] + bias[col];
            float ge = 0.5f * v * (1.0f + erff(v * 0.7071067811865476f));
            h1[row * HID + col] = f2b(ge);
        }
    }
}

// ------- fc2: h1 @ w_fc2T, split-K x2 -> raw fp32 partials -----------------
// Grid (4,36,2) = 288 blocks; fc2_red does the reduce + bias + residual.
// Pfc ALIASES the t1|qb|kb|vT region (Ppj is dead after ln_kernel).
__global__ void fc2_kernel(const short* __restrict__ h1, const short* __restrict__ wT,
                           float* __restrict__ Pfc)
{
    __shared__ short lds[2 * 64 * GSTRIDE];
    f32x4 acc[4];
    const int m0 = blockIdx.y * 64, n0 = blockIdx.x * 64, z = blockIdx.z;
    mfma_gemm_core<512, 1024>(h1, wT, m0, n0, z * 512, acc, lds);
    const int lane = threadIdx.x & 63, w = threadIdx.x >> 6;
    const int quad = lane >> 4, l15 = lane & 15;
    float* out = Pfc + z * (NN * CC);
    #pragma unroll
    for (int c = 0; c < 4; ++c) {
        int col = n0 + c * 16 + l15;
        #pragma unroll
        for (int r = 0; r < 4; ++r) {
            int row = m0 + w * 16 + quad * 4 + r;
            out[row * CC + col] = acc[c][r];
        }
    }
}

// ------- fc2 reduce: out = sum(Pfc) + b_fc2 + x2 ---------------------------
__global__ void fc2_red(const float* __restrict__ Pfc, const float* __restrict__ bias,
                        const float* __restrict__ x2, float* __restrict__ out)
{
    const int i = blockIdx.x * CC + threadIdx.x;
    const int NC = NN * CC;
    out[i] = Pfc[i] + Pfc[NC + i] + bias[threadIdx.x] + x2[i];
}

extern "C" void kernel_launch(void* const* d_in, const int* in_sizes, int n_in,
                              void* d_out, int out_size, void* d_ws, size_t ws_size,
                              hipStream_t stream)
{
    const float* x          = (const float*)d_in[0];
    const float* gamma1     = (const float*)d_in[1];
    const float* beta1      = (const float*)d_in[2];
    const float* w_qkv      = (const float*)d_in[3];
    const float* w_proj     = (const float*)d_in[4];
    const float* b_proj     = (const float*)d_in[5];
    const float* bias_table = (const float*)d_in[6];
    const float* gamma2     = (const float*)d_in[7];
    const float* beta2      = (const float*)d_in[8];
    const float* w_fc1      = (const float*)d_in[9];
    const float* b_fc1      = (const float*)d_in[10];
    const float* w_fc2      = (const float*)d_in[11];
    const float* b_fc2      = (const float*)d_in[12];
    // d_in[13] = rel_idx (int32) — unused: bias index computed analytically.

    short* S = (short*)d_ws;
    const int NC = NN * CC;               // 589824
    short* t1     = S;                    // bf16 [N][C]
    short* qb     = t1  + NC;             // bf16 [h][n][d]
    short* kb     = qb  + NC;             // bf16 [h][n][d]
    short* vT     = kb  + NC;             // bf16 [h][d][n]
    short* obuf   = vT  + NC;             // bf16 [N][C]
    short* t2     = obuf+ NC;             // bf16 [N][C]
    short* h1     = t2  + NC;             // bf16 [N][HID]
    short* wTqkv  = h1  + NN * HID;       // bf16 [768][256]
    short* wTproj = wTqkv  + 768 * 256;   // bf16 [256][256]
    short* wTfc1  = wTproj + 256 * 256;   // bf16 [1024][256]
    short* wTfc2  = wTfc1  + 1024 * 256;  // bf16 [256][1024]
    short* biasT  = wTfc2  + 256 * 1024;  // bf16 [NH][9025] (pre-scaled by LOG2E)
    float* x2     = (float*)(biasT + NH * NBIAS + 8);  // fp32 [N][C]
    // Partial buffers ALIAS dead regions (keep footprint at round-0 level):
    //   Ppj [2][N][C] fp32 = 4*NC shorts -> exactly t1|qb|kb|vT (dead post-attn)
    //   Pfc [2][N][C] fp32 -> same region (Ppj dead after ln_kernel)
    float* Ppj    = (float*)t1;
    float* Pfc    = (float*)t1;

    prep_kernel<<<NN + 64, 256, 0, stream>>>(x, gamma1, beta1, t1,
                                             bias_table, biasT);
    wtrans_kernel<<<768, 256, 0, stream>>>(w_qkv, w_proj, w_fc1, w_fc2,
                                           wTqkv, wTproj, wTfc1, wTfc2);
    qkv_kernel<<<dim3(12, 36), 256, 0, stream>>>(t1, wTqkv, qb, kb, vT);
    attn_kernel<<<1152, 256, 0, stream>>>(qb, kb, vT, biasT, obuf);
    proj_kernel<<<dim3(4, 36, 2), 256, 0, stream>>>(obuf, wTproj, Ppj);
    ln_kernel<<<NN, 256, 0, stream>>>(Ppj, Ppj + NC, b_proj, x,
                                      gamma2, beta2, t2, x2);
    fc1_kernel<<<dim3(16, 36), 256, 0, stream>>>(t2, wTfc1, b_fc1, h1);
    fc2_kernel<<<dim3(4, 36, 2), 256, 0, stream>>>(h1, wTfc2, Pfc);
    fc2_red<<<NN, 256, 0, stream>>>(Pfc, b_fc2, x2, (float*)d_out);
}

// Round 8
// 161.000 us; speedup vs baseline: 1.1734x; 1.0501x over previous
//
#include <hip/hip_runtime.h>
#include <hip/hip_bf16.h>
#include <math.h>

#define IH 48
#define IW 48
#define NN 2304          // N = IH*IW
#define CC 256           // channels
#define NH 8
#define HD 32
#define HID 1024
#define NBIAS 9025       // (2*48-1)^2
#define SCALE 0.17677669529663687f
#define LOG2E 1.4426950408889634f
#define LN_EPS 1e-5f

typedef __attribute__((ext_vector_type(8))) short bf16x8;   // 8 bf16 in 4 VGPRs
typedef __attribute__((ext_vector_type(4))) float f32x4;

__device__ __forceinline__ short f2b(float f) {
    __hip_bfloat16 h = __float2bfloat16(f);
    short s; __builtin_memcpy(&s, &h, 2); return s;
}
__device__ __forceinline__ float b2f(short s) {
    __hip_bfloat16 h; __builtin_memcpy(&h, &s, 2); return __bfloat162float(h);
}
__device__ __forceinline__ float fast_exp2(float x) {
#if __has_builtin(__builtin_amdgcn_exp2f)
    return __builtin_amdgcn_exp2f(x);     // single v_exp_f32
#else
    return exp2f(x);
#endif
}

// ------- Prep (single launch): ln1 | coalesced weight transpose | bias -----
// blocks [0,NN): LayerNorm rows.
// blocks [NN, NN+768): 32x32-tile f32->bf16 transposes (both sides coalesced;
//   round-5/7 lesson: the old gather form read stride-768/1024 4B = terrible).
// blocks [NN+768, ...): bias table [9025][8] -> [8][9025] bf16 * LOG2E.
__global__ void prep_kernel(const float* __restrict__ x, const float* __restrict__ g,
                            const float* __restrict__ b, short* __restrict__ t1,
                            const float* __restrict__ bt, short* __restrict__ o_bias,
                            const float* __restrict__ w_qkv, const float* __restrict__ w_proj,
                            const float* __restrict__ w_fc1, const float* __restrict__ w_fc2,
                            short* __restrict__ o_qkv, short* __restrict__ o_proj,
                            short* __restrict__ o_fc1, short* __restrict__ o_fc2)
{
    __shared__ float tsh[32][33];
    __shared__ float red[8];
    const int bid = blockIdx.x, tid = threadIdx.x;
    if (bid < NN) {        // ---- LayerNorm row ----
        float v = x[bid * CC + tid];
        float s = v, s2 = v * v;
        #pragma unroll
        for (int off = 32; off > 0; off >>= 1) {
            s  += __shfl_xor(s, off);
            s2 += __shfl_xor(s2, off);
        }
        const int wid = tid >> 6;
        if ((tid & 63) == 0) { red[wid * 2] = s; red[wid * 2 + 1] = s2; }
        __syncthreads();
        float tot  = red[0] + red[2] + red[4] + red[6];
        float tot2 = red[1] + red[3] + red[5] + red[7];
        float mu   = tot * (1.0f / CC);
        float var  = tot2 * (1.0f / CC) - mu * mu;
        float rstd = rsqrtf(var + LN_EPS);
        t1[bid * CC + tid] = f2b((v - mu) * rstd * g[tid] + b[tid]);
        return;
    }
    if (bid < NN + 768) {  // ---- weight transpose tile ----
        int bb = bid - NN;
        const float* src; short* dst; int K, Nn, kt, nt;
        if (bb < 192)      { src = w_qkv;  dst = o_qkv;  K = 256;  Nn = 768;  kt = bb / 24; nt = bb % 24; }
        else if (bb < 256) { bb -= 192; src = w_proj; dst = o_proj; K = 256;  Nn = 256;  kt = bb / 8;  nt = bb % 8; }
        else if (bb < 512) { bb -= 256; src = w_fc1;  dst = o_fc1;  K = 256;  Nn = 1024; kt = bb / 32; nt = bb % 32; }
        else               { bb -= 512; src = w_fc2;  dst = o_fc2;  K = 1024; Nn = 256;  kt = bb / 8;  nt = bb % 8; }
        const int r = tid >> 5, c = tid & 31;
        const int k0 = kt * 32, n0 = nt * 32;
        #pragma unroll
        for (int i = 0; i < 4; ++i)
            tsh[r + i * 8][c] = src[(k0 + r + i * 8) * Nn + n0 + c];
        __syncthreads();
        #pragma unroll
        for (int i = 0; i < 4; ++i)
            dst[(n0 + r + i * 8) * K + k0 + c] = f2b(tsh[c][r + i * 8]);
        return;
    }
    // ---- bias table conversion, read-coalesced ----
    const int stride = (gridDim.x - NN - 768) * 256;
    for (int i = (bid - NN - 768) * 256 + tid; i < NBIAS * NH; i += stride) {
        int idx = i >> 3, h = i & 7;
        o_bias[h * NBIAS + idx] = f2b(bt[i] * LOG2E);
    }
}

// ---------------- LayerNorm (standalone, for ln2) --------------------------
__global__ void ln_kernel(const float* __restrict__ x,
                          const float* __restrict__ g,
                          const float* __restrict__ b,
                          short* __restrict__ out)
{
    __shared__ float red[8];
    const int row = blockIdx.x, tid = threadIdx.x;
    float v = x[row * CC + tid];
    float s = v, s2 = v * v;
    #pragma unroll
    for (int off = 32; off > 0; off >>= 1) {
        s  += __shfl_xor(s, off);
        s2 += __shfl_xor(s2, off);
    }
    const int wid = tid >> 6;
    if ((tid & 63) == 0) { red[wid * 2] = s; red[wid * 2 + 1] = s2; }
    __syncthreads();
    float tot  = red[0] + red[2] + red[4] + red[6];
    float tot2 = red[1] + red[3] + red[5] + red[7];
    float mu   = tot * (1.0f / CC);
    float var  = tot2 * (1.0f / CC) - mu * mu;
    float rstd = rsqrtf(var + LN_EPS);
    out[row * CC + tid] = f2b((v - mu) * rstd * g[tid] + b[tid]);
}

// --- MFMA GEMM core: TM x 64 tile, TM/16 waves, K-step 64, reg-pipelined ---
// TM=64: 256 threads (4 waves). TM=32: 128 threads (2 waves) -> 2x blocks for
// the grid-starved proj/fc2 GEMMs with NO extra launches or reduce passes.
#define GSTRIDE 72
template<int KLEN, int KSTR, int TM>
__device__ __forceinline__ void mfma_gemm_core(const short* __restrict__ A,
                                               const short* __restrict__ BT,
                                               int m0, int n0, int kb, f32x4 acc[4],
                                               short* lds)
{
    short* As = lds;                 // [TM][72]
    short* Bs = lds + TM * GSTRIDE;  // [64][72]
    const int tid  = threadIdx.x;
    const int w    = tid >> 6, lane = tid & 63;
    const int quad = lane >> 4, l15 = lane & 15;
    const int sr = tid >> 2;            // A staging row 0..TM-1 (threads/4==TM)
    const int sc = (tid & 3) * 16;      // k-granule 0,16,32,48
    #pragma unroll
    for (int c = 0; c < 4; ++c) acc[c] = (f32x4){0.f, 0.f, 0.f, 0.f};

    const short* Ap = &A [(m0 + sr) * KSTR + kb + sc];
    const short* Bp = &BT[(n0 + sr) * KSTR + kb + sc];
    bf16x8 ra0 = *(const bf16x8*)Ap,       ra1 = *(const bf16x8*)(Ap + 8);
    bf16x8 rb0 = *(const bf16x8*)Bp,       rb1 = *(const bf16x8*)(Bp + 8);
    bf16x8 rc0, rc1;
    const short* Bp2 = Bp;
    if constexpr (TM == 32) {           // second B-row block (rows 32..63)
        Bp2 = &BT[(n0 + sr + 32) * KSTR + kb + sc];
        rc0 = *(const bf16x8*)Bp2;  rc1 = *(const bf16x8*)(Bp2 + 8);
    }

    for (int k0 = 0; k0 < KLEN; k0 += 64) {
        __syncthreads();                       // LDS consumers of tile k-1 done
        *(bf16x8*)&As[sr * GSTRIDE + sc]     = ra0;
        *(bf16x8*)&As[sr * GSTRIDE + sc + 8] = ra1;
        *(bf16x8*)&Bs[sr * GSTRIDE + sc]     = rb0;
        *(bf16x8*)&Bs[sr * GSTRIDE + sc + 8] = rb1;
        if constexpr (TM == 32) {
            *(bf16x8*)&Bs[(sr + 32) * GSTRIDE + sc]     = rc0;
            *(bf16x8*)&Bs[(sr + 32) * GSTRIDE + sc + 8] = rc1;
        }
        if (k0 + 64 < KLEN) {                  // prefetch tile k+1 (overlaps below)
            ra0 = *(const bf16x8*)(Ap + k0 + 64);
            ra1 = *(const bf16x8*)(Ap + k0 + 72);
            rb0 = *(const bf16x8*)(Bp + k0 + 64);
            rb1 = *(const bf16x8*)(Bp + k0 + 72);
            if constexpr (TM == 32) {
                rc0 = *(const bf16x8*)(Bp2 + k0 + 64);
                rc1 = *(const bf16x8*)(Bp2 + k0 + 72);
            }
        }
        __syncthreads();                       // tile k visible
        #pragma unroll
        for (int s = 0; s < 2; ++s) {
            bf16x8 a = *(const bf16x8*)&As[(w * 16 + l15) * GSTRIDE + s * 32 + quad * 8];
            #pragma unroll
            for (int c = 0; c < 4; ++c) {
                bf16x8 b = *(const bf16x8*)&Bs[(c * 16 + l15) * GSTRIDE + s * 32 + quad * 8];
                acc[c] = __builtin_amdgcn_mfma_f32_16x16x32_bf16(a, b, acc[c], 0, 0, 0);
            }
        }
    }
}
// C/D layout [m89]: col = n-tile*16 + (lane&15), row = 16w + quad*4 + reg.

// ---------------- QKV: t1 @ w_qkvT -> qb, kb (bf16 [h][n][d]), vT [h][d][n]-
// q is pre-scaled by SCALE*LOG2E so attention softmax can use exp2 directly.
__global__ void qkv_kernel(const short* __restrict__ t1, const short* __restrict__ wT,
                           short* __restrict__ qb, short* __restrict__ kb,
                           short* __restrict__ vT)
{
    __shared__ short lds[2 * 64 * GSTRIDE];
    f32x4 acc[4];
    const int m0 = blockIdx.y * 64, n0 = blockIdx.x * 64;
    mfma_gemm_core<256, 256, 64>(t1, wT, m0, n0, 0, acc, lds);
    const int lane = threadIdx.x & 63, w = threadIdx.x >> 6;
    const int quad = lane >> 4, l15 = lane & 15;
    #pragma unroll
    for (int c = 0; c < 4; ++c) {
        int col = n0 + c * 16 + l15;
        int three = col >> 8, rem = col & 255;
        int h = rem >> 5, d = rem & 31;
        #pragma unroll
        for (int r = 0; r < 4; ++r) {
            int row = m0 + w * 16 + quad * 4 + r;
            float v = acc[c][r];
            if (three == 0)      qb[(h * NN + row) * HD + d] = f2b(v * (SCALE * LOG2E));
            else if (three == 1) kb[(h * NN + row) * HD + d] = f2b(v);
            else                 vT[(h * HD + d) * NN + row] = f2b(v);
        }
    }
}

// -------- MFMA flash attention: round-1 structure + bias LDS window --------
// block=(head,16q), 4 waves x 576 keys, P via per-wave LDS round-trip.
// Bias: 48x63 bf16 window staged coalesced once per block (validated r4->5).
#define PSTRIDE 40    // sbuf row stride: 80 B (16B-aligned, conflict-free b128)
__global__ __launch_bounds__(256) void attn_kernel(
        const short* __restrict__ qb, const short* __restrict__ kb,
        const short* __restrict__ vT, const short* __restrict__ biasT,
        short* __restrict__ o)
{
    __shared__ float Ored[4][16][33];
    __shared__ float lred[4][16];
    __shared__ short sbuf[4][16 * PSTRIDE];
    __shared__ short bwin[48][64];
    const int w = threadIdx.x >> 6, lane = threadIdx.x & 63;
    const int quad = lane >> 4, l15 = lane & 15;
    const int h = blockIdx.x / 144, q0 = (blockIdx.x % 144) * 16;
    const int t0 = w * 576;
    short* sb = &sbuf[w][0];
    const short* bt = &biasT[h * NBIAS];

    // per-block q coords: 16-row q-tiles never straddle image rows (16 | 48)
    const int qi = q0 / IW, qj0 = q0 % IW;

    // ---- stage the 48x63 bias window, coalesced ----
    for (int idx = threadIdx.x; idx < 48 * 63; idx += 256) {
        int kr = idx / 63, cc = idx - kr * 63;
        bwin[kr][cc] = bt[(qi - kr + 47) * 95 + qj0 + cc];
    }

    // Q fragment: A[m=lane&15][k=quad*8+j]  (q pre-scaled by SCALE*LOG2E)
    bf16x8 qf = *(const bf16x8*)&qb[(h * NN + q0 + l15) * HD + quad * 8];

    f32x4 O0 = (f32x4){0.f,0.f,0.f,0.f}, O1 = (f32x4){0.f,0.f,0.f,0.f};
    float lp[4] = {0.f, 0.f, 0.f, 0.f};
    const f32x4 zero = (f32x4){0.f,0.f,0.f,0.f};

    __syncthreads();                       // bias window visible

    for (int c = 0; c < 18; ++c) {
        const int t = t0 + c * 32;
        bf16x8 k0f = *(const bf16x8*)&kb[(h * NN + t      + l15) * HD + quad * 8];
        bf16x8 k1f = *(const bf16x8*)&kb[(h * NN + t + 16 + l15) * HD + quad * 8];
        f32x4 s0 = __builtin_amdgcn_mfma_f32_16x16x32_bf16(qf, k0f, zero, 0, 0, 0);
        f32x4 s1 = __builtin_amdgcn_mfma_f32_16x16x32_bf16(qf, k1f, zero, 0, 0, 0);
        bf16x8 v0 = *(const bf16x8*)&vT[(h * HD + l15)      * NN + t + quad * 8];
        bf16x8 v1 = *(const bf16x8*)&vT[(h * HD + 16 + l15) * NN + t + quad * 8];

        // bias from LDS window: 16-key halves never straddle image rows
        const int ki0 = t / IW,        kj0_ = t - ki0 * IW;
        const int ki1 = (t + 16) / IW, kj1_ = (t + 16) - ki1 * IW;
        const int cA = quad * 4 + 47 - kj0_ - l15;
        const int cB = quad * 4 + 47 - kj1_ - l15;

        #pragma unroll
        for (int r = 0; r < 4; ++r) {
            float p0 = fast_exp2(s0[r] + b2f(bwin[ki0][cA + r]));
            float p1 = fast_exp2(s1[r] + b2f(bwin[ki1][cB + r]));
            lp[r] += p0 + p1;
            sb[(quad * 4 + r) * PSTRIDE + l15]      = f2b(p0);
            sb[(quad * 4 + r) * PSTRIDE + 16 + l15] = f2b(p1);
        }
        // Per-wave private LDS round-trip; DS pipe is in-order within a wave.
        asm volatile("s_waitcnt lgkmcnt(0)" ::: "memory");
        bf16x8 pa = *(const bf16x8*)&sb[l15 * PSTRIDE + quad * 8];
        O0 = __builtin_amdgcn_mfma_f32_16x16x32_bf16(pa, v0, O0, 0, 0, 0);
        O1 = __builtin_amdgcn_mfma_f32_16x16x32_bf16(pa, v1, O1, 0, 0, 0);
    }

    #pragma unroll
    for (int r = 0; r < 4; ++r) {
        float l = lp[r];
        l += __shfl_xor(l, 1); l += __shfl_xor(l, 2);
        l += __shfl_xor(l, 4); l += __shfl_xor(l, 8);
        if (l15 == 0) lred[w][quad * 4 + r] = l;
        Ored[w][quad * 4 + r][l15]      = O0[r];
        Ored[w][quad * 4 + r][16 + l15] = O1[r];
    }
    __syncthreads();
    {   // 256 threads combine 16 q-rows x 32 dims (2 rows per thread)
        const int col = threadIdx.x & 31;
        for (int rr = threadIdx.x >> 5; rr < 16; rr += 8) {
            float s = 0.f, l = 0.f;
            #pragma unroll
            for (int pw = 0; pw < 4; ++pw) { s += Ored[pw][rr][col]; l += lred[pw][rr]; }
            o[(q0 + rr) * CC + h * HD + col] = f2b(s / l);
        }
    }
}

// ------- proj: o @ w_projT + b_proj + x -> x2 (fp32), 32-row tiles ---------
// Grid (4,72) = 288 blocks of 128 threads (2x the old 144 at zero extra cost).
__global__ void proj_kernel(const short* __restrict__ o, const short* __restrict__ wT,
                            const float* __restrict__ bias, const float* __restrict__ x_in,
                            float* __restrict__ x2)
{
    __shared__ short lds[(32 + 64) * GSTRIDE];
    f32x4 acc[4];
    const int m0 = blockIdx.y * 32, n0 = blockIdx.x * 64;
    mfma_gemm_core<256, 256, 32>(o, wT, m0, n0, 0, acc, lds);
    const int lane = threadIdx.x & 63, w = threadIdx.x >> 6;
    const int quad = lane >> 4, l15 = lane & 15;
    #pragma unroll
    for (int c = 0; c < 4; ++c) {
        int col = n0 + c * 16 + l15;
        #pragma unroll
        for (int r = 0; r < 4; ++r) {
            int row = m0 + w * 16 + quad * 4 + r;
            x2[row * CC + col] = acc[c][r] + bias[col] + x_in[row * CC + col];
        }
    }
}

// ---------------- fc1: t2 @ w_fc1T + b_fc1, GELU -> h1 (bf16) --------------
__global__ void fc1_kernel(const short* __restrict__ t2, const short* __restrict__ wT,
                           const float* __restrict__ bias, short* __restrict__ h1)
{
    __shared__ short lds[2 * 64 * GSTRIDE];
    f32x4 acc[4];
    const int m0 = blockIdx.y * 64, n0 = blockIdx.x * 64;
    mfma_gemm_core<256, 256, 64>(t2, wT, m0, n0, 0, acc, lds);
    const int lane = threadIdx.x & 63, w = threadIdx.x >> 6;
    const int quad = lane >> 4, l15 = lane & 15;
    #pragma unroll
    for (int c = 0; c < 4; ++c) {
        int col = n0 + c * 16 + l15;
        #pragma unroll
        for (int r = 0; r < 4; ++r) {
            int row = m0 + w * 16 + quad * 4 + r;
            float v = acc[c][r] + bias[col];
            float ge = 0.5f * v * (1.0f + erff(v * 0.7071067811865476f));
            h1[row * HID + col] = f2b(ge);
        }
    }
}

// ------- fc2: h1 @ w_fc2T + b_fc2 + x2 -> out (fp32), 32-row tiles ---------
// Grid (4,72) = 288 blocks of 128 threads.
__global__ void fc2_kernel(const short* __restrict__ h1, const short* __restrict__ wT,
                           const float* __restrict__ bias, const float* __restrict__ x2,
                           float* __restrict__ out)
{
    __shared__ short lds[(32 + 64) * GSTRIDE];
    f32x4 acc[4];
    const int m0 = blockIdx.y * 32, n0 = blockIdx.x * 64;
    mfma_gemm_core<1024, 1024, 32>(h1, wT, m0, n0, 0, acc, lds);
    const int lane = threadIdx.x & 63, w = threadIdx.x >> 6;
    const int quad = lane >> 4, l15 = lane & 15;
    #pragma unroll
    for (int c = 0; c < 4; ++c) {
        int col = n0 + c * 16 + l15;
        #pragma unroll
        for (int r = 0; r < 4; ++r) {
            int row = m0 + w * 16 + quad * 4 + r;
            out[row * CC + col] = acc[c][r] + bias[col] + x2[row * CC + col];
        }
    }
}

extern "C" void kernel_launch(void* const* d_in, const int* in_sizes, int n_in,
                              void* d_out, int out_size, void* d_ws, size_t ws_size,
                              hipStream_t stream)
{
    const float* x          = (const float*)d_in[0];
    const float* gamma1     = (const float*)d_in[1];
    const float* beta1      = (const float*)d_in[2];
    const float* w_qkv      = (const float*)d_in[3];
    const float* w_proj     = (const float*)d_in[4];
    const float* b_proj     = (const float*)d_in[5];
    const float* bias_table = (const float*)d_in[6];
    const float* gamma2     = (const float*)d_in[7];
    const float* beta2      = (const float*)d_in[8];
    const float* w_fc1      = (const float*)d_in[9];
    const float* b_fc1      = (const float*)d_in[10];
    const float* w_fc2      = (const float*)d_in[11];
    const float* b_fc2      = (const float*)d_in[12];
    // d_in[13] = rel_idx (int32) — unused: bias index computed analytically.

    short* S = (short*)d_ws;
    const int NC = NN * CC;               // 589824
    short* t1     = S;                    // bf16 [N][C]
    short* qb     = t1  + NC;             // bf16 [h][n][d]
    short* kb     = qb  + NC;             // bf16 [h][n][d]
    short* vT     = kb  + NC;             // bf16 [h][d][n]
    short* obuf   = vT  + NC;             // bf16 [N][C]
    short* t2     = obuf+ NC;             // bf16 [N][C]
    short* h1     = t2  + NC;             // bf16 [N][HID]
    short* wTqkv  = h1  + NN * HID;       // bf16 [768][256]
    short* wTproj = wTqkv  + 768 * 256;   // bf16 [256][256]
    short* wTfc1  = wTproj + 256 * 256;   // bf16 [1024][256]
    short* wTfc2  = wTfc1  + 1024 * 256;  // bf16 [256][1024]
    short* biasT  = wTfc2  + 256 * 1024;  // bf16 [NH][9025] (pre-scaled by LOG2E)
    float* x2     = (float*)(biasT + NH * NBIAS + 8);  // fp32 [N][C]

    prep_kernel<<<NN + 768 + 64, 256, 0, stream>>>(x, gamma1, beta1, t1,
                                                   bias_table, biasT,
                                                   w_qkv, w_proj, w_fc1, w_fc2,
                                                   wTqkv, wTproj, wTfc1, wTfc2);
    qkv_kernel<<<dim3(12, 36), 256, 0, stream>>>(t1, wTqkv, qb, kb, vT);
    attn_kernel<<<1152, 256, 0, stream>>>(qb, kb, vT, biasT, obuf);
    proj_kernel<<<dim3(4, 72), 128, 0, stream>>>(obuf, wTproj, b_proj, x, x2);
    ln_kernel<<<NN, 256, 0, stream>>>(x2, gamma2, beta2, t2);
    fc1_kernel<<<dim3(16, 36), 256, 0, stream>>>(t2, wTfc1, b_fc1, h1);
    fc2_kernel<<<dim3(4, 72), 128, 0, stream>>>(h1, wTfc2, b_fc2, x2,
                                                (float*)d_out);
}